// Round 1
// baseline (665.043 us; speedup 1.0000x reference)
//
#include <hip/hip_runtime.h>

#define N_NODES 50000
#define N_EDGES 800000
#define D 128
#define N_LAYERS 3

// ---------------- edge dtype detection (int64 vs int32) ----------------
// If edge_index arrived as int64, every odd 32-bit word (high half) is 0
// (values are in [0, 50000)). If int32, odd words are random indices.
__global__ void detect_dtype_kernel(const unsigned int* __restrict__ edge, int* __restrict__ flag) {
    __shared__ int any_nz;
    if (threadIdx.x == 0) any_nz = 0;
    __syncthreads();
    int nz = 0;
    for (int i = threadIdx.x; i < 2048; i += blockDim.x) {
        if (edge[2 * i + 1] != 0u) nz = 1;
    }
    if (nz) atomicOr(&any_nz, 1);
    __syncthreads();
    if (threadIdx.x == 0) *flag = any_nz ? 0 : 1;   // 1 => int64 layout
}

__global__ void convert_edges_kernel(const int* __restrict__ edge, const int* __restrict__ flag,
                                     int* __restrict__ src, int* __restrict__ dst) {
    int i = blockIdx.x * blockDim.x + threadIdx.x;
    if (i >= N_EDGES) return;
    if (*flag) {  // int64: low words at even positions
        src[i] = edge[2 * (size_t)i];
        dst[i] = edge[2 * ((size_t)N_EDGES + i)];
    } else {      // int32
        src[i] = edge[i];
        dst[i] = edge[N_EDGES + i];
    }
}

// ---------------- CSR build ----------------
__global__ void hist_kernel(const int* __restrict__ dst, int* __restrict__ deg) {
    int e = blockIdx.x * blockDim.x + threadIdx.x;
    if (e < N_EDGES) atomicAdd(&deg[dst[e]], 1);
}

__global__ __launch_bounds__(1024) void scan_kernel(const int* __restrict__ deg,
                                                    int* __restrict__ offsets,
                                                    int* __restrict__ cursor,
                                                    float* __restrict__ inv_deg) {
    __shared__ int tsum[1024];
    const int CH = (N_NODES + 1023) / 1024;  // 49
    int t = threadIdx.x;
    int start = t * CH;
    int end = min(start + CH, N_NODES);
    int s = 0;
    for (int i = start; i < end; ++i) s += deg[i];
    tsum[t] = s;
    __syncthreads();
    for (int off = 1; off < 1024; off <<= 1) {
        int v = (t >= off) ? tsum[t - off] : 0;
        __syncthreads();
        tsum[t] += v;
        __syncthreads();
    }
    int run = (t == 0) ? 0 : tsum[t - 1];
    for (int i = start; i < end; ++i) {
        int d = deg[i];
        offsets[i] = run;
        cursor[i] = run;
        inv_deg[i] = 1.0f / (float)max(d, 1);
        run += d;
    }
    if (t == 1023) offsets[N_NODES] = tsum[1023];
}

__global__ void bucket_kernel(const int* __restrict__ src, const int* __restrict__ dst,
                              int* __restrict__ cursor, int* __restrict__ csr_src) {
    int e = blockIdx.x * blockDim.x + threadIdx.x;
    if (e >= N_EDGES) return;
    int d = dst[e];
    int pos = atomicAdd(&cursor[d], 1);
    csr_src[pos] = src[e];
}

// ---------------- weight pre-transpose: W2[l][k][j] ----------------
// k < 128: Wl[l][j][k]; k >= 128: Wr[l][j][k-128]
__global__ void prep_w_kernel(const float* __restrict__ Wl, const float* __restrict__ Wr,
                              float* __restrict__ W2) {
    int idx = blockIdx.x * blockDim.x + threadIdx.x;
    if (idx >= N_LAYERS * 256 * 128) return;
    int j = idx & 127;
    int k = (idx >> 7) & 255;
    int l = idx >> 15;
    float v;
    if (k < 128) v = Wl[((size_t)l * 128 + j) * 128 + k];
    else         v = Wr[((size_t)l * 128 + j) * 128 + (k - 128)];
    W2[idx] = v;
}

// ---------------- mean aggregation: wave per node ----------------
__global__ __launch_bounds__(256) void aggregate_kernel(const float* __restrict__ h,
                                                        const int* __restrict__ offsets,
                                                        const int* __restrict__ csr_src,
                                                        const float* __restrict__ inv_deg,
                                                        float* __restrict__ agg) {
    int node = blockIdx.x * 4 + (threadIdx.x >> 6);
    int lane = threadIdx.x & 63;
    if (node >= N_NODES) return;
    int beg = offsets[node];
    int end = offsets[node + 1];
    float2 acc = make_float2(0.f, 0.f);
    const float2* hp = reinterpret_cast<const float2*>(h);
    for (int e = beg; e < end; ++e) {
        int s = csr_src[e];
        float2 v = hp[(size_t)s * 64 + lane];
        acc.x += v.x;
        acc.y += v.y;
    }
    float w = inv_deg[node];
    reinterpret_cast<float2*>(agg)[(size_t)node * 64 + lane] = make_float2(acc.x * w, acc.y * w);
}

// ---------------- fused GEMM: out = [agg|h] @ W2 + bias (+ReLU) ----------------
// BM=64 rows, BN=128 (full), BK=32. 256 threads: tj=tid&15 (8 cols), tm=tid>>4 (4 rows).
template <int RELU>
__global__ __launch_bounds__(256) void gemm_kernel(const float* __restrict__ Aagg,
                                                   const float* __restrict__ Hin,
                                                   const float* __restrict__ W2,
                                                   const float* __restrict__ bias,
                                                   float* __restrict__ Out) {
    __shared__ float As[64][33];   // +1 pad breaks bank conflicts on column reads
    __shared__ float Ws[32][128];
    int tid = threadIdx.x;
    int tj = tid & 15, tm = tid >> 4;
    int j0 = tj * 8, m0 = tm * 4;
    int blockRow = blockIdx.x * 64;

    float acc[4][8];
#pragma unroll
    for (int i = 0; i < 4; ++i)
#pragma unroll
        for (int j = 0; j < 8; ++j) acc[i][j] = 0.f;

    for (int kc = 0; kc < 256; kc += 32) {
        const float* Asrc = (kc < 128) ? Aagg : Hin;
        int kbase = (kc < 128) ? kc : (kc - 128);
        // stage A: 64 rows x 32 k
#pragma unroll
        for (int s = 0; s < 2; ++s) {
            int slot = tid + s * 256;     // 0..511 float4 slots
            int m = slot >> 3;            // 8 float4 per row
            int kq = slot & 7;
            int row = blockRow + m;
            float4 v = make_float4(0.f, 0.f, 0.f, 0.f);
            if (row < N_NODES)
                v = *reinterpret_cast<const float4*>(&Asrc[(size_t)row * 128 + kbase + kq * 4]);
            As[m][kq * 4 + 0] = v.x;
            As[m][kq * 4 + 1] = v.y;
            As[m][kq * 4 + 2] = v.z;
            As[m][kq * 4 + 3] = v.w;
        }
        // stage W chunk: 32 k x 128 j
#pragma unroll
        for (int s = 0; s < 4; ++s) {
            int slot = tid + s * 256;     // 0..1023 float4 slots
            int k = slot >> 5;
            int jq = slot & 31;
            float4 v = *reinterpret_cast<const float4*>(&W2[(size_t)(kc + k) * 128 + jq * 4]);
            *reinterpret_cast<float4*>(&Ws[k][jq * 4]) = v;
        }
        __syncthreads();
#pragma unroll 8
        for (int k = 0; k < 32; ++k) {
            float a0 = As[m0 + 0][k];
            float a1 = As[m0 + 1][k];
            float a2 = As[m0 + 2][k];
            float a3 = As[m0 + 3][k];
            float4 wlo = *reinterpret_cast<const float4*>(&Ws[k][j0]);
            float4 whi = *reinterpret_cast<const float4*>(&Ws[k][j0 + 4]);
            float w[8] = {wlo.x, wlo.y, wlo.z, wlo.w, whi.x, whi.y, whi.z, whi.w};
#pragma unroll
            for (int j = 0; j < 8; ++j) {
                acc[0][j] = fmaf(a0, w[j], acc[0][j]);
                acc[1][j] = fmaf(a1, w[j], acc[1][j]);
                acc[2][j] = fmaf(a2, w[j], acc[2][j]);
                acc[3][j] = fmaf(a3, w[j], acc[3][j]);
            }
        }
        __syncthreads();
    }
    float b[8];
#pragma unroll
    for (int j = 0; j < 8; ++j) b[j] = bias[j0 + j];
#pragma unroll
    for (int i = 0; i < 4; ++i) {
        int row = blockRow + m0 + i;
        if (row >= N_NODES) continue;
#pragma unroll
        for (int q = 0; q < 2; ++q) {
            float4 o;
            o.x = acc[i][q * 4 + 0] + b[q * 4 + 0];
            o.y = acc[i][q * 4 + 1] + b[q * 4 + 1];
            o.z = acc[i][q * 4 + 2] + b[q * 4 + 2];
            o.w = acc[i][q * 4 + 3] + b[q * 4 + 3];
            if (RELU) {
                o.x = fmaxf(o.x, 0.f);
                o.y = fmaxf(o.y, 0.f);
                o.z = fmaxf(o.z, 0.f);
                o.w = fmaxf(o.w, 0.f);
            }
            *reinterpret_cast<float4*>(&Out[(size_t)row * 128 + j0 + q * 4]) = o;
        }
    }
}

extern "C" void kernel_launch(void* const* d_in, const int* in_sizes, int n_in,
                              void* d_out, int out_size, void* d_ws, size_t ws_size,
                              hipStream_t stream) {
    const float* x  = (const float*)d_in[0];
    const int*   ei = (const int*)d_in[1];
    const float* Wl = (const float*)d_in[2];
    const float* bl = (const float*)d_in[3];
    const float* Wr = (const float*)d_in[4];
    float* out = (float*)d_out;
    char* ws = (char*)d_ws;

    int*   flag   = (int*)(ws + 0);
    int*   deg    = (int*)(ws + 512);
    int*   offs   = (int*)(ws + 201216);
    int*   cursor = (int*)(ws + 401920);
    float* invd   = (float*)(ws + 602624);
    int*   src    = (int*)(ws + 803328);
    int*   dst    = (int*)(ws + 4003840);
    int*   csr    = (int*)(ws + 7204352);
    float* W2     = (float*)(ws + 10404864);
    float* agg    = (float*)(ws + 10798592);
    float* bufA   = (float*)(ws + 36398592);   // total ws use ~62 MB

    hipMemsetAsync(deg, 0, N_NODES * sizeof(int), stream);
    detect_dtype_kernel<<<1, 256, 0, stream>>>((const unsigned int*)ei, flag);
    convert_edges_kernel<<<(N_EDGES + 255) / 256, 256, 0, stream>>>(ei, flag, src, dst);
    hist_kernel<<<(N_EDGES + 255) / 256, 256, 0, stream>>>(dst, deg);
    scan_kernel<<<1, 1024, 0, stream>>>(deg, offs, cursor, invd);
    bucket_kernel<<<(N_EDGES + 255) / 256, 256, 0, stream>>>(src, dst, cursor, csr);
    prep_w_kernel<<<(N_LAYERS * 256 * 128 + 255) / 256, 256, 0, stream>>>(Wl, Wr, W2);

    const int aggGrid = N_NODES / 4;            // 12500
    const int gemmGrid = (N_NODES + 63) / 64;   // 782

    // layer 0: x -> bufA (ReLU)
    aggregate_kernel<<<aggGrid, 256, 0, stream>>>(x, offs, csr, invd, agg);
    gemm_kernel<1><<<gemmGrid, 256, 0, stream>>>(agg, x, W2 + 0 * 256 * 128, bl + 0, bufA);
    // layer 1: bufA -> out (ReLU)
    aggregate_kernel<<<aggGrid, 256, 0, stream>>>(bufA, offs, csr, invd, agg);
    gemm_kernel<1><<<gemmGrid, 256, 0, stream>>>(agg, bufA, W2 + 1 * 256 * 128, bl + 128, out);
    // layer 2: out -> out (no ReLU; GEMM blocks only read their own rows before writing them)
    aggregate_kernel<<<aggGrid, 256, 0, stream>>>(out, offs, csr, invd, agg);
    gemm_kernel<0><<<gemmGrid, 256, 0, stream>>>(agg, out, W2 + 2 * 256 * 128, bl + 256, out);
}

// Round 2
// 532.153 us; speedup vs baseline: 1.2497x; 1.2497x over previous
//
#include <hip/hip_runtime.h>

#define N_NODES 50000
#define N_EDGES 800000
#define D 128
#define N_LAYERS 3
#define SCAN_NBLK ((N_NODES + 255) / 256)   // 196

// ---------------- edge dtype detection (int64 vs int32) ----------------
__global__ void detect_dtype_kernel(const unsigned int* __restrict__ edge, int* __restrict__ flag) {
    __shared__ int any_nz;
    if (threadIdx.x == 0) any_nz = 0;
    __syncthreads();
    int nz = 0;
    for (int i = threadIdx.x; i < 2048; i += blockDim.x) {
        if (edge[2 * i + 1] != 0u) nz = 1;
    }
    if (nz) atomicOr(&any_nz, 1);
    __syncthreads();
    if (threadIdx.x == 0) *flag = any_nz ? 0 : 1;   // 1 => int64 layout
}

// convert + degree histogram fused (one pass over edges)
__global__ void convert_hist_kernel(const int* __restrict__ edge, const int* __restrict__ flag,
                                    int* __restrict__ src, int* __restrict__ dst,
                                    int* __restrict__ deg) {
    int i = blockIdx.x * blockDim.x + threadIdx.x;
    if (i >= N_EDGES) return;
    int s, d;
    if (*flag) {  // int64: low words at even positions
        s = edge[2 * (size_t)i];
        d = edge[2 * ((size_t)N_EDGES + i)];
    } else {      // int32
        s = edge[i];
        d = edge[N_EDGES + i];
    }
    src[i] = s;
    dst[i] = d;
    atomicAdd(&deg[d], 1);
}

// ---------------- hierarchical exclusive scan over deg[50000] ----------------
__global__ __launch_bounds__(256) void partial_sum_kernel(const int* __restrict__ deg,
                                                          int* __restrict__ partials) {
    __shared__ int s[256];
    int i = blockIdx.x * 256 + threadIdx.x;
    int v = (i < N_NODES) ? deg[i] : 0;
    s[threadIdx.x] = v;
    __syncthreads();
    for (int off = 128; off > 0; off >>= 1) {
        if (threadIdx.x < off) s[threadIdx.x] += s[threadIdx.x + off];
        __syncthreads();
    }
    if (threadIdx.x == 0) partials[blockIdx.x] = s[0];
}

__global__ __launch_bounds__(256) void scan_partials_kernel(int* __restrict__ partials,
                                                            int* __restrict__ offsets) {
    __shared__ int s[256];
    int t = threadIdx.x;
    int v = (t < SCAN_NBLK) ? partials[t] : 0;
    s[t] = v;
    __syncthreads();
    for (int off = 1; off < 256; off <<= 1) {
        int u = (t >= off) ? s[t - off] : 0;
        __syncthreads();
        s[t] += u;
        __syncthreads();
    }
    if (t < SCAN_NBLK) partials[t] = s[t] - v;   // exclusive
    if (t == 255) offsets[N_NODES] = s[255];     // total
}

__global__ __launch_bounds__(256) void scan_final_kernel(const int* __restrict__ deg,
                                                         const int* __restrict__ partials,
                                                         int* __restrict__ offsets,
                                                         int* __restrict__ cursor,
                                                         float* __restrict__ inv_deg) {
    __shared__ int s[256];
    int t = threadIdx.x;
    int i = blockIdx.x * 256 + t;
    int v = (i < N_NODES) ? deg[i] : 0;
    s[t] = v;
    __syncthreads();
    for (int off = 1; off < 256; off <<= 1) {
        int u = (t >= off) ? s[t - off] : 0;
        __syncthreads();
        s[t] += u;
        __syncthreads();
    }
    if (i < N_NODES) {
        int excl = partials[blockIdx.x] + s[t] - v;
        offsets[i] = excl;
        cursor[i] = excl;
        inv_deg[i] = 1.0f / (float)max(v, 1);
    }
}

__global__ void bucket_kernel(const int* __restrict__ src, const int* __restrict__ dst,
                              int* __restrict__ cursor, int* __restrict__ csr_src) {
    int e = blockIdx.x * blockDim.x + threadIdx.x;
    if (e >= N_EDGES) return;
    int d = dst[e];
    int pos = atomicAdd(&cursor[d], 1);
    csr_src[pos] = src[e];
}

// ---------------- weight pre-transpose: W2[l][k][j] ----------------
__global__ void prep_w_kernel(const float* __restrict__ Wl, const float* __restrict__ Wr,
                              float* __restrict__ W2) {
    int idx = blockIdx.x * blockDim.x + threadIdx.x;
    if (idx >= N_LAYERS * 256 * 128) return;
    int j = idx & 127;
    int k = (idx >> 7) & 255;
    int l = idx >> 15;
    float v;
    if (k < 128) v = Wl[((size_t)l * 128 + j) * 128 + k];
    else         v = Wr[((size_t)l * 128 + j) * 128 + (k - 128)];
    W2[idx] = v;
}

// ---------------- mean aggregation: wave per node ----------------
__global__ __launch_bounds__(256) void aggregate_kernel(const float* __restrict__ h,
                                                        const int* __restrict__ offsets,
                                                        const int* __restrict__ csr_src,
                                                        const float* __restrict__ inv_deg,
                                                        float* __restrict__ agg) {
    int node = blockIdx.x * 4 + (threadIdx.x >> 6);
    int lane = threadIdx.x & 63;
    if (node >= N_NODES) return;
    int beg = offsets[node];
    int end = offsets[node + 1];
    float2 acc = make_float2(0.f, 0.f);
    const float2* hp = reinterpret_cast<const float2*>(h);
    for (int e = beg; e < end; ++e) {
        int s = csr_src[e];
        float2 v = hp[(size_t)s * 64 + lane];
        acc.x += v.x;
        acc.y += v.y;
    }
    float w = inv_deg[node];
    reinterpret_cast<float2*>(agg)[(size_t)node * 64 + lane] = make_float2(acc.x * w, acc.y * w);
}

// ---------------- fused GEMM: out = [agg|h] @ W2 + bias (+ReLU) ----------------
template <int RELU>
__global__ __launch_bounds__(256) void gemm_kernel(const float* __restrict__ Aagg,
                                                   const float* __restrict__ Hin,
                                                   const float* __restrict__ W2,
                                                   const float* __restrict__ bias,
                                                   float* __restrict__ Out) {
    __shared__ float As[64][33];
    __shared__ float Ws[32][128];
    int tid = threadIdx.x;
    int tj = tid & 15, tm = tid >> 4;
    int j0 = tj * 8, m0 = tm * 4;
    int blockRow = blockIdx.x * 64;

    float acc[4][8];
#pragma unroll
    for (int i = 0; i < 4; ++i)
#pragma unroll
        for (int j = 0; j < 8; ++j) acc[i][j] = 0.f;

    for (int kc = 0; kc < 256; kc += 32) {
        const float* Asrc = (kc < 128) ? Aagg : Hin;
        int kbase = (kc < 128) ? kc : (kc - 128);
#pragma unroll
        for (int s = 0; s < 2; ++s) {
            int slot = tid + s * 256;
            int m = slot >> 3;
            int kq = slot & 7;
            int row = blockRow + m;
            float4 v = make_float4(0.f, 0.f, 0.f, 0.f);
            if (row < N_NODES)
                v = *reinterpret_cast<const float4*>(&Asrc[(size_t)row * 128 + kbase + kq * 4]);
            As[m][kq * 4 + 0] = v.x;
            As[m][kq * 4 + 1] = v.y;
            As[m][kq * 4 + 2] = v.z;
            As[m][kq * 4 + 3] = v.w;
        }
#pragma unroll
        for (int s = 0; s < 4; ++s) {
            int slot = tid + s * 256;
            int k = slot >> 5;
            int jq = slot & 31;
            float4 v = *reinterpret_cast<const float4*>(&W2[(size_t)(kc + k) * 128 + jq * 4]);
            *reinterpret_cast<float4*>(&Ws[k][jq * 4]) = v;
        }
        __syncthreads();
#pragma unroll 8
        for (int k = 0; k < 32; ++k) {
            float a0 = As[m0 + 0][k];
            float a1 = As[m0 + 1][k];
            float a2 = As[m0 + 2][k];
            float a3 = As[m0 + 3][k];
            float4 wlo = *reinterpret_cast<const float4*>(&Ws[k][j0]);
            float4 whi = *reinterpret_cast<const float4*>(&Ws[k][j0 + 4]);
            float w[8] = {wlo.x, wlo.y, wlo.z, wlo.w, whi.x, whi.y, whi.z, whi.w};
#pragma unroll
            for (int j = 0; j < 8; ++j) {
                acc[0][j] = fmaf(a0, w[j], acc[0][j]);
                acc[1][j] = fmaf(a1, w[j], acc[1][j]);
                acc[2][j] = fmaf(a2, w[j], acc[2][j]);
                acc[3][j] = fmaf(a3, w[j], acc[3][j]);
            }
        }
        __syncthreads();
    }
    float b[8];
#pragma unroll
    for (int j = 0; j < 8; ++j) b[j] = bias[j0 + j];
#pragma unroll
    for (int i = 0; i < 4; ++i) {
        int row = blockRow + m0 + i;
        if (row >= N_NODES) continue;
#pragma unroll
        for (int q = 0; q < 2; ++q) {
            float4 o;
            o.x = acc[i][q * 4 + 0] + b[q * 4 + 0];
            o.y = acc[i][q * 4 + 1] + b[q * 4 + 1];
            o.z = acc[i][q * 4 + 2] + b[q * 4 + 2];
            o.w = acc[i][q * 4 + 3] + b[q * 4 + 3];
            if (RELU) {
                o.x = fmaxf(o.x, 0.f);
                o.y = fmaxf(o.y, 0.f);
                o.z = fmaxf(o.z, 0.f);
                o.w = fmaxf(o.w, 0.f);
            }
            *reinterpret_cast<float4*>(&Out[(size_t)row * 128 + j0 + q * 4]) = o;
        }
    }
}

extern "C" void kernel_launch(void* const* d_in, const int* in_sizes, int n_in,
                              void* d_out, int out_size, void* d_ws, size_t ws_size,
                              hipStream_t stream) {
    const float* x  = (const float*)d_in[0];
    const int*   ei = (const int*)d_in[1];
    const float* Wl = (const float*)d_in[2];
    const float* bl = (const float*)d_in[3];
    const float* Wr = (const float*)d_in[4];
    float* out = (float*)d_out;
    char* ws = (char*)d_ws;

    int*   flag     = (int*)(ws + 0);
    int*   partials = (int*)(ws + 256);
    int*   deg      = (int*)(ws + 1536);
    int*   offs     = (int*)(ws + 202240);
    int*   cursor   = (int*)(ws + 402944);
    float* invd     = (float*)(ws + 603648);
    int*   src      = (int*)(ws + 804352);
    int*   dst      = (int*)(ws + 4004864);
    int*   csr      = (int*)(ws + 7205376);
    float* W2       = (float*)(ws + 10405888);
    float* agg      = (float*)(ws + 10799616);
    float* bufA     = (float*)(ws + 36399616);   // total ws use ~62 MB

    hipMemsetAsync(deg, 0, N_NODES * sizeof(int), stream);
    detect_dtype_kernel<<<1, 256, 0, stream>>>((const unsigned int*)ei, flag);
    convert_hist_kernel<<<(N_EDGES + 255) / 256, 256, 0, stream>>>(ei, flag, src, dst, deg);
    partial_sum_kernel<<<SCAN_NBLK, 256, 0, stream>>>(deg, partials);
    scan_partials_kernel<<<1, 256, 0, stream>>>(partials, offs);
    scan_final_kernel<<<SCAN_NBLK, 256, 0, stream>>>(deg, partials, offs, cursor, invd);
    bucket_kernel<<<(N_EDGES + 255) / 256, 256, 0, stream>>>(src, dst, cursor, csr);
    prep_w_kernel<<<(N_LAYERS * 256 * 128 + 255) / 256, 256, 0, stream>>>(Wl, Wr, W2);

    const int aggGrid = N_NODES / 4;            // 12500
    const int gemmGrid = (N_NODES + 63) / 64;   // 782

    // layer 0: x -> bufA (ReLU)
    aggregate_kernel<<<aggGrid, 256, 0, stream>>>(x, offs, csr, invd, agg);
    gemm_kernel<1><<<gemmGrid, 256, 0, stream>>>(agg, x, W2 + 0 * 256 * 128, bl + 0, bufA);
    // layer 1: bufA -> out (ReLU)
    aggregate_kernel<<<aggGrid, 256, 0, stream>>>(bufA, offs, csr, invd, agg);
    gemm_kernel<1><<<gemmGrid, 256, 0, stream>>>(agg, bufA, W2 + 1 * 256 * 128, bl + 128, out);
    // layer 2: out -> out (no ReLU)
    aggregate_kernel<<<aggGrid, 256, 0, stream>>>(out, offs, csr, invd, agg);
    gemm_kernel<0><<<gemmGrid, 256, 0, stream>>>(agg, out, W2 + 2 * 256 * 128, bl + 256, out);
}

// Round 3
// 434.361 us; speedup vs baseline: 1.5311x; 1.2251x over previous
//
#include <hip/hip_runtime.h>

#define N_NODES 50000
#define N_EDGES 800000
#define D 128
#define N_LAYERS 3
#define SCAN_NBLK ((N_NODES + 255) / 256)   // 196

// ---------------- edge dtype detection (int64 vs int32) ----------------
__global__ void detect_dtype_kernel(const unsigned int* __restrict__ edge, int* __restrict__ flag) {
    __shared__ int any_nz;
    if (threadIdx.x == 0) any_nz = 0;
    __syncthreads();
    int nz = 0;
    for (int i = threadIdx.x; i < 2048; i += blockDim.x) {
        if (edge[2 * i + 1] != 0u) nz = 1;
    }
    if (nz) atomicOr(&any_nz, 1);
    __syncthreads();
    if (threadIdx.x == 0) *flag = any_nz ? 0 : 1;   // 1 => int64 layout
}

// convert + degree histogram fused (one pass over edges)
__global__ void convert_hist_kernel(const int* __restrict__ edge, const int* __restrict__ flag,
                                    int* __restrict__ src, int* __restrict__ dst,
                                    int* __restrict__ deg) {
    int i = blockIdx.x * blockDim.x + threadIdx.x;
    if (i >= N_EDGES) return;
    int s, d;
    if (*flag) {  // int64: low words at even positions
        s = edge[2 * (size_t)i];
        d = edge[2 * ((size_t)N_EDGES + i)];
    } else {      // int32
        s = edge[i];
        d = edge[N_EDGES + i];
    }
    src[i] = s;
    dst[i] = d;
    atomicAdd(&deg[d], 1);
}

// ---------------- hierarchical exclusive scan over deg[50000] ----------------
__global__ __launch_bounds__(256) void partial_sum_kernel(const int* __restrict__ deg,
                                                          int* __restrict__ partials) {
    __shared__ int s[256];
    int i = blockIdx.x * 256 + threadIdx.x;
    int v = (i < N_NODES) ? deg[i] : 0;
    s[threadIdx.x] = v;
    __syncthreads();
    for (int off = 128; off > 0; off >>= 1) {
        if (threadIdx.x < off) s[threadIdx.x] += s[threadIdx.x + off];
        __syncthreads();
    }
    if (threadIdx.x == 0) partials[blockIdx.x] = s[0];
}

__global__ __launch_bounds__(256) void scan_partials_kernel(int* __restrict__ partials,
                                                            int* __restrict__ offsets) {
    __shared__ int s[256];
    int t = threadIdx.x;
    int v = (t < SCAN_NBLK) ? partials[t] : 0;
    s[t] = v;
    __syncthreads();
    for (int off = 1; off < 256; off <<= 1) {
        int u = (t >= off) ? s[t - off] : 0;
        __syncthreads();
        s[t] += u;
        __syncthreads();
    }
    if (t < SCAN_NBLK) partials[t] = s[t] - v;   // exclusive
    if (t == 255) offsets[N_NODES] = s[255];     // total
}

__global__ __launch_bounds__(256) void scan_final_kernel(const int* __restrict__ deg,
                                                         const int* __restrict__ partials,
                                                         int* __restrict__ offsets,
                                                         int* __restrict__ cursor,
                                                         float* __restrict__ inv_deg) {
    __shared__ int s[256];
    int t = threadIdx.x;
    int i = blockIdx.x * 256 + t;
    int v = (i < N_NODES) ? deg[i] : 0;
    s[t] = v;
    __syncthreads();
    for (int off = 1; off < 256; off <<= 1) {
        int u = (t >= off) ? s[t - off] : 0;
        __syncthreads();
        s[t] += u;
        __syncthreads();
    }
    if (i < N_NODES) {
        int excl = partials[blockIdx.x] + s[t] - v;
        offsets[i] = excl;
        cursor[i] = excl;
        inv_deg[i] = 1.0f / (float)max(v, 1);
    }
}

__global__ void bucket_kernel(const int* __restrict__ src, const int* __restrict__ dst,
                              int* __restrict__ cursor, int* __restrict__ csr_src) {
    int e = blockIdx.x * blockDim.x + threadIdx.x;
    if (e >= N_EDGES) return;
    int d = dst[e];
    int pos = atomicAdd(&cursor[d], 1);
    csr_src[pos] = src[e];
}

// ---------------- weight pre-transpose: W2[l][k][j] ----------------
__global__ void prep_w_kernel(const float* __restrict__ Wl, const float* __restrict__ Wr,
                              float* __restrict__ W2) {
    int idx = blockIdx.x * blockDim.x + threadIdx.x;
    if (idx >= N_LAYERS * 256 * 128) return;
    int j = idx & 127;
    int k = (idx >> 7) & 255;
    int l = idx >> 15;
    float v;
    if (k < 128) v = Wl[((size_t)l * 128 + j) * 128 + k];
    else         v = Wr[((size_t)l * 128 + j) * 128 + (k - 128)];
    W2[idx] = v;
}

// ---------------- mean aggregation: wave per node, float4 x 2-edge ILP ----------------
// 32 lanes x float4 = one 512B row; two wave-halves take alternating edges;
// manual unroll x2 -> 4 independent row-gathers in flight per iteration.
__global__ __launch_bounds__(256) void aggregate_kernel(const float* __restrict__ h,
                                                        const int* __restrict__ offsets,
                                                        const int* __restrict__ csr_src,
                                                        const float* __restrict__ inv_deg,
                                                        float* __restrict__ agg) {
    int node = blockIdx.x * 4 + (threadIdx.x >> 6);
    int lane = threadIdx.x & 63;
    int half = lane >> 5;
    int col = lane & 31;
    if (node >= N_NODES) return;
    int beg = offsets[node];
    int end = offsets[node + 1];
    const float4* hp = reinterpret_cast<const float4*>(h);
    float4 a0 = make_float4(0.f, 0.f, 0.f, 0.f);
    float4 a1 = make_float4(0.f, 0.f, 0.f, 0.f);
    int e = beg + half;
    for (; e + 2 < end; e += 4) {
        int s0 = csr_src[e];
        int s1 = csr_src[e + 2];
        float4 v0 = hp[(size_t)s0 * 32 + col];
        float4 v1 = hp[(size_t)s1 * 32 + col];
        a0.x += v0.x; a0.y += v0.y; a0.z += v0.z; a0.w += v0.w;
        a1.x += v1.x; a1.y += v1.y; a1.z += v1.z; a1.w += v1.w;
    }
    if (e < end) {
        int s0 = csr_src[e];
        float4 v0 = hp[(size_t)s0 * 32 + col];
        a0.x += v0.x; a0.y += v0.y; a0.z += v0.z; a0.w += v0.w;
    }
    float4 acc;
    acc.x = a0.x + a1.x;
    acc.y = a0.y + a1.y;
    acc.z = a0.z + a1.z;
    acc.w = a0.w + a1.w;
    acc.x += __shfl_xor(acc.x, 32, 64);
    acc.y += __shfl_xor(acc.y, 32, 64);
    acc.z += __shfl_xor(acc.z, 32, 64);
    acc.w += __shfl_xor(acc.w, 32, 64);
    if (half == 0) {
        float w = inv_deg[node];
        reinterpret_cast<float4*>(agg)[(size_t)node * 32 + col] =
            make_float4(acc.x * w, acc.y * w, acc.z * w, acc.w * w);
    }
}

// ---------------- fused GEMM: out = [agg|h] @ W2 + bias (+ReLU) ----------------
template <int RELU>
__global__ __launch_bounds__(256) void gemm_kernel(const float* __restrict__ Aagg,
                                                   const float* __restrict__ Hin,
                                                   const float* __restrict__ W2,
                                                   const float* __restrict__ bias,
                                                   float* __restrict__ Out) {
    __shared__ float As[64][33];
    __shared__ float Ws[32][128];
    int tid = threadIdx.x;
    int tj = tid & 15, tm = tid >> 4;
    int j0 = tj * 8, m0 = tm * 4;
    int blockRow = blockIdx.x * 64;

    float acc[4][8];
#pragma unroll
    for (int i = 0; i < 4; ++i)
#pragma unroll
        for (int j = 0; j < 8; ++j) acc[i][j] = 0.f;

    for (int kc = 0; kc < 256; kc += 32) {
        const float* Asrc = (kc < 128) ? Aagg : Hin;
        int kbase = (kc < 128) ? kc : (kc - 128);
#pragma unroll
        for (int s = 0; s < 2; ++s) {
            int slot = tid + s * 256;
            int m = slot >> 3;
            int kq = slot & 7;
            int row = blockRow + m;
            float4 v = make_float4(0.f, 0.f, 0.f, 0.f);
            if (row < N_NODES)
                v = *reinterpret_cast<const float4*>(&Asrc[(size_t)row * 128 + kbase + kq * 4]);
            As[m][kq * 4 + 0] = v.x;
            As[m][kq * 4 + 1] = v.y;
            As[m][kq * 4 + 2] = v.z;
            As[m][kq * 4 + 3] = v.w;
        }
#pragma unroll
        for (int s = 0; s < 4; ++s) {
            int slot = tid + s * 256;
            int k = slot >> 5;
            int jq = slot & 31;
            float4 v = *reinterpret_cast<const float4*>(&W2[(size_t)(kc + k) * 128 + jq * 4]);
            *reinterpret_cast<float4*>(&Ws[k][jq * 4]) = v;
        }
        __syncthreads();
#pragma unroll 8
        for (int k = 0; k < 32; ++k) {
            float a0 = As[m0 + 0][k];
            float a1 = As[m0 + 1][k];
            float a2 = As[m0 + 2][k];
            float a3 = As[m0 + 3][k];
            float4 wlo = *reinterpret_cast<const float4*>(&Ws[k][j0]);
            float4 whi = *reinterpret_cast<const float4*>(&Ws[k][j0 + 4]);
            float w[8] = {wlo.x, wlo.y, wlo.z, wlo.w, whi.x, whi.y, whi.z, whi.w};
#pragma unroll
            for (int j = 0; j < 8; ++j) {
                acc[0][j] = fmaf(a0, w[j], acc[0][j]);
                acc[1][j] = fmaf(a1, w[j], acc[1][j]);
                acc[2][j] = fmaf(a2, w[j], acc[2][j]);
                acc[3][j] = fmaf(a3, w[j], acc[3][j]);
            }
        }
        __syncthreads();
    }
    float b[8];
#pragma unroll
    for (int j = 0; j < 8; ++j) b[j] = bias[j0 + j];
#pragma unroll
    for (int i = 0; i < 4; ++i) {
        int row = blockRow + m0 + i;
        if (row >= N_NODES) continue;
#pragma unroll
        for (int q = 0; q < 2; ++q) {
            float4 o;
            o.x = acc[i][q * 4 + 0] + b[q * 4 + 0];
            o.y = acc[i][q * 4 + 1] + b[q * 4 + 1];
            o.z = acc[i][q * 4 + 2] + b[q * 4 + 2];
            o.w = acc[i][q * 4 + 3] + b[q * 4 + 3];
            if (RELU) {
                o.x = fmaxf(o.x, 0.f);
                o.y = fmaxf(o.y, 0.f);
                o.z = fmaxf(o.z, 0.f);
                o.w = fmaxf(o.w, 0.f);
            }
            *reinterpret_cast<float4*>(&Out[(size_t)row * 128 + j0 + q * 4]) = o;
        }
    }
}

extern "C" void kernel_launch(void* const* d_in, const int* in_sizes, int n_in,
                              void* d_out, int out_size, void* d_ws, size_t ws_size,
                              hipStream_t stream) {
    const float* x  = (const float*)d_in[0];
    const int*   ei = (const int*)d_in[1];
    const float* Wl = (const float*)d_in[2];
    const float* bl = (const float*)d_in[3];
    const float* Wr = (const float*)d_in[4];
    float* out = (float*)d_out;
    char* ws = (char*)d_ws;

    int*   flag     = (int*)(ws + 0);
    int*   partials = (int*)(ws + 256);
    int*   deg      = (int*)(ws + 1536);
    int*   offs     = (int*)(ws + 202240);
    int*   cursor   = (int*)(ws + 402944);
    float* invd     = (float*)(ws + 603648);
    int*   src      = (int*)(ws + 804352);
    int*   dst      = (int*)(ws + 4004864);
    int*   csr      = (int*)(ws + 7205376);
    float* W2       = (float*)(ws + 10405888);
    float* agg      = (float*)(ws + 10799616);
    float* bufA     = (float*)(ws + 36399616);   // total ws use ~62 MB

    hipMemsetAsync(deg, 0, N_NODES * sizeof(int), stream);
    detect_dtype_kernel<<<1, 256, 0, stream>>>((const unsigned int*)ei, flag);
    convert_hist_kernel<<<(N_EDGES + 255) / 256, 256, 0, stream>>>(ei, flag, src, dst, deg);
    partial_sum_kernel<<<SCAN_NBLK, 256, 0, stream>>>(deg, partials);
    scan_partials_kernel<<<1, 256, 0, stream>>>(partials, offs);
    scan_final_kernel<<<SCAN_NBLK, 256, 0, stream>>>(deg, partials, offs, cursor, invd);
    bucket_kernel<<<(N_EDGES + 255) / 256, 256, 0, stream>>>(src, dst, cursor, csr);
    prep_w_kernel<<<(N_LAYERS * 256 * 128 + 255) / 256, 256, 0, stream>>>(Wl, Wr, W2);

    const int aggGrid = N_NODES / 4;            // 12500
    const int gemmGrid = (N_NODES + 63) / 64;   // 782

    // layer 0: x -> bufA (ReLU)
    aggregate_kernel<<<aggGrid, 256, 0, stream>>>(x, offs, csr, invd, agg);
    gemm_kernel<1><<<gemmGrid, 256, 0, stream>>>(agg, x, W2 + 0 * 256 * 128, bl + 0, bufA);
    // layer 1: bufA -> out (ReLU)
    aggregate_kernel<<<aggGrid, 256, 0, stream>>>(bufA, offs, csr, invd, agg);
    gemm_kernel<1><<<gemmGrid, 256, 0, stream>>>(agg, bufA, W2 + 1 * 256 * 128, bl + 128, out);
    // layer 2: out -> out (no ReLU)
    aggregate_kernel<<<aggGrid, 256, 0, stream>>>(out, offs, csr, invd, agg);
    gemm_kernel<0><<<gemmGrid, 256, 0, stream>>>(agg, out, W2 + 2 * 256 * 128, bl + 256, out);
}

// Round 4
// 380.463 us; speedup vs baseline: 1.7480x; 1.1417x over previous
//
#include <hip/hip_runtime.h>

#define N_NODES 50000
#define N_EDGES 800000
#define D 128
#define N_LAYERS 3
#define SCAN_NBLK ((N_NODES + 255) / 256)   // 196

typedef __attribute__((ext_vector_type(8))) short bfrag;
typedef __attribute__((ext_vector_type(4))) float f32x4;

__device__ __forceinline__ unsigned short f2bf_rn(float f) {
    union { float f; unsigned u; } a; a.f = f;
    unsigned r = a.u + 0x7fffu + ((a.u >> 16) & 1u);
    return (unsigned short)(r >> 16);
}
__device__ __forceinline__ float bf2f(unsigned short h) {
    union { unsigned u; float f; } a; a.u = ((unsigned)h) << 16;
    return a.f;
}

#define GLOAD16(g, l) __builtin_amdgcn_global_load_lds( \
    (const __attribute__((address_space(1))) void*)(g), \
    (__attribute__((address_space(3))) void*)(l), 16, 0, 0)

// ---------------- edge dtype detection (int64 vs int32) ----------------
__global__ void detect_dtype_kernel(const unsigned int* __restrict__ edge, int* __restrict__ flag) {
    __shared__ int any_nz;
    if (threadIdx.x == 0) any_nz = 0;
    __syncthreads();
    int nz = 0;
    for (int i = threadIdx.x; i < 2048; i += blockDim.x) {
        if (edge[2 * i + 1] != 0u) nz = 1;
    }
    if (nz) atomicOr(&any_nz, 1);
    __syncthreads();
    if (threadIdx.x == 0) *flag = any_nz ? 0 : 1;   // 1 => int64 layout
}

__global__ void convert_hist_kernel(const int* __restrict__ edge, const int* __restrict__ flag,
                                    int* __restrict__ src, int* __restrict__ dst,
                                    int* __restrict__ deg) {
    int i = blockIdx.x * blockDim.x + threadIdx.x;
    if (i >= N_EDGES) return;
    int s, d;
    if (*flag) {
        s = edge[2 * (size_t)i];
        d = edge[2 * ((size_t)N_EDGES + i)];
    } else {
        s = edge[i];
        d = edge[N_EDGES + i];
    }
    src[i] = s;
    dst[i] = d;
    atomicAdd(&deg[d], 1);
}

// ---------------- hierarchical exclusive scan ----------------
__global__ __launch_bounds__(256) void partial_sum_kernel(const int* __restrict__ deg,
                                                          int* __restrict__ partials) {
    __shared__ int s[256];
    int i = blockIdx.x * 256 + threadIdx.x;
    int v = (i < N_NODES) ? deg[i] : 0;
    s[threadIdx.x] = v;
    __syncthreads();
    for (int off = 128; off > 0; off >>= 1) {
        if (threadIdx.x < off) s[threadIdx.x] += s[threadIdx.x + off];
        __syncthreads();
    }
    if (threadIdx.x == 0) partials[blockIdx.x] = s[0];
}

__global__ __launch_bounds__(256) void scan_partials_kernel(int* __restrict__ partials,
                                                            int* __restrict__ offsets) {
    __shared__ int s[256];
    int t = threadIdx.x;
    int v = (t < SCAN_NBLK) ? partials[t] : 0;
    s[t] = v;
    __syncthreads();
    for (int off = 1; off < 256; off <<= 1) {
        int u = (t >= off) ? s[t - off] : 0;
        __syncthreads();
        s[t] += u;
        __syncthreads();
    }
    if (t < SCAN_NBLK) partials[t] = s[t] - v;
    if (t == 255) offsets[N_NODES] = s[255];
}

__global__ __launch_bounds__(256) void scan_final_kernel(const int* __restrict__ deg,
                                                         const int* __restrict__ partials,
                                                         int* __restrict__ offsets,
                                                         int* __restrict__ cursor,
                                                         float* __restrict__ inv_deg) {
    __shared__ int s[256];
    int t = threadIdx.x;
    int i = blockIdx.x * 256 + t;
    int v = (i < N_NODES) ? deg[i] : 0;
    s[t] = v;
    __syncthreads();
    for (int off = 1; off < 256; off <<= 1) {
        int u = (t >= off) ? s[t - off] : 0;
        __syncthreads();
        s[t] += u;
        __syncthreads();
    }
    if (i < N_NODES) {
        int excl = partials[blockIdx.x] + s[t] - v;
        offsets[i] = excl;
        cursor[i] = excl;
        inv_deg[i] = 1.0f / (float)max(v, 1);
    }
}

__global__ void bucket_kernel(const int* __restrict__ src, const int* __restrict__ dst,
                              int* __restrict__ cursor, int* __restrict__ csr_src) {
    int e = blockIdx.x * blockDim.x + threadIdx.x;
    if (e >= N_EDGES) return;
    int d = dst[e];
    int pos = atomicAdd(&cursor[d], 1);
    csr_src[pos] = src[e];
}

// ---------------- weight split: Wt[l][j][k] (k contiguous), hi/lo bf16 ----------------
// k<128 -> W_l[l][j][k]; k>=128 -> W_r[l][j][k-128]
__global__ void prep_w_kernel(const float* __restrict__ Wl, const float* __restrict__ Wr,
                              unsigned short* __restrict__ WH, unsigned short* __restrict__ WL) {
    int idx = blockIdx.x * blockDim.x + threadIdx.x;
    if (idx >= N_LAYERS * 128 * 256) return;
    int k = idx & 255;
    int j = (idx >> 8) & 127;
    int l = idx >> 15;
    float v = (k < 128) ? Wl[((size_t)l * 128 + j) * 128 + k]
                        : Wr[((size_t)l * 128 + j) * 128 + (k - 128)];
    unsigned short hi = f2bf_rn(v);
    WH[idx] = hi;
    WL[idx] = f2bf_rn(v - bf2f(hi));
}

// ---------------- x split: fp32 -> bf16 hi/lo ----------------
__global__ void split_x_kernel(const float* __restrict__ x,
                               unsigned short* __restrict__ H, unsigned short* __restrict__ L) {
    int t = blockIdx.x * 256 + threadIdx.x;   // over N_NODES*32 float4s
    if (t >= N_NODES * 32) return;
    float4 v = reinterpret_cast<const float4*>(x)[t];
    ushort4 h, l;
    h.x = f2bf_rn(v.x); l.x = f2bf_rn(v.x - bf2f(h.x));
    h.y = f2bf_rn(v.y); l.y = f2bf_rn(v.y - bf2f(h.y));
    h.z = f2bf_rn(v.z); l.z = f2bf_rn(v.z - bf2f(h.z));
    h.w = f2bf_rn(v.w); l.w = f2bf_rn(v.w - bf2f(h.w));
    reinterpret_cast<ushort4*>(H)[t] = h;
    reinterpret_cast<ushort4*>(L)[t] = l;
}

// ---------------- mean aggregation: wave per node, bf16 hi/lo output ----------------
__global__ __launch_bounds__(256) void aggregate_kernel(const float* __restrict__ h,
                                                        const int* __restrict__ offsets,
                                                        const int* __restrict__ csr_src,
                                                        const float* __restrict__ inv_deg,
                                                        unsigned short* __restrict__ aggH,
                                                        unsigned short* __restrict__ aggL) {
    int node = blockIdx.x * 4 + (threadIdx.x >> 6);
    int lane = threadIdx.x & 63;
    int half = lane >> 5;
    int col = lane & 31;
    if (node >= N_NODES) return;
    int beg = offsets[node];
    int end = offsets[node + 1];
    const float4* hp = reinterpret_cast<const float4*>(h);
    float4 a0 = make_float4(0.f, 0.f, 0.f, 0.f);
    float4 a1 = make_float4(0.f, 0.f, 0.f, 0.f);
    int e = beg + half;
    for (; e + 2 < end; e += 4) {
        int s0 = csr_src[e];
        int s1 = csr_src[e + 2];
        float4 v0 = hp[(size_t)s0 * 32 + col];
        float4 v1 = hp[(size_t)s1 * 32 + col];
        a0.x += v0.x; a0.y += v0.y; a0.z += v0.z; a0.w += v0.w;
        a1.x += v1.x; a1.y += v1.y; a1.z += v1.z; a1.w += v1.w;
    }
    if (e < end) {
        int s0 = csr_src[e];
        float4 v0 = hp[(size_t)s0 * 32 + col];
        a0.x += v0.x; a0.y += v0.y; a0.z += v0.z; a0.w += v0.w;
    }
    float4 acc;
    acc.x = a0.x + a1.x;
    acc.y = a0.y + a1.y;
    acc.z = a0.z + a1.z;
    acc.w = a0.w + a1.w;
    acc.x += __shfl_xor(acc.x, 32, 64);
    acc.y += __shfl_xor(acc.y, 32, 64);
    acc.z += __shfl_xor(acc.z, 32, 64);
    acc.w += __shfl_xor(acc.w, 32, 64);
    if (half == 0) {
        float w = inv_deg[node];
        float vx = acc.x * w, vy = acc.y * w, vz = acc.z * w, vw = acc.w * w;
        ushort4 hi, lo;
        hi.x = f2bf_rn(vx); lo.x = f2bf_rn(vx - bf2f(hi.x));
        hi.y = f2bf_rn(vy); lo.y = f2bf_rn(vy - bf2f(hi.y));
        hi.z = f2bf_rn(vz); lo.z = f2bf_rn(vz - bf2f(hi.z));
        hi.w = f2bf_rn(vw); lo.w = f2bf_rn(vw - bf2f(hi.w));
        *reinterpret_cast<ushort4*>(&aggH[(size_t)node * 128 + col * 4]) = hi;
        *reinterpret_cast<ushort4*>(&aggL[(size_t)node * 128 + col * 4]) = lo;
    }
}

// ---------------- MFMA GEMM: C = [agg|h] @ Wt^T + bias, split-bf16 3-term ----------------
// Block: 64 rows x 128 cols, 4 waves (wave w owns rows w*16..w*16+15).
// K=256 in 8 steps of 32. W tile staged to LDS [kchunk 4][j 128][8] via global_load_lds.
// A fragments loaded global->reg (wave-private rows). In-place bf16 out (BH may == hH).
template <int RELU, int LAST>
__global__ __launch_bounds__(256) void mfma_gemm_kernel(
    const unsigned short* __restrict__ aggH, const unsigned short* __restrict__ aggL,
    const unsigned short* hH, const unsigned short* hL,
    const unsigned short* __restrict__ WH, const unsigned short* __restrict__ WL,
    const float* __restrict__ bias,
    float* __restrict__ OutF, unsigned short* BH, unsigned short* BL)
{
    __shared__ __align__(16) unsigned short Bh[4][128][8];
    __shared__ __align__(16) unsigned short Bl[4][128][8];
    const int tid = threadIdx.x;
    const int lane = tid & 63;
    const int wv = tid >> 6;           // 0..3
    const int m16 = lane & 15;
    const int kg = lane >> 4;          // 0..3
    const int blockRow = blockIdx.x * 64;
    const int rowg = blockRow + wv * 16 + m16;
    const int rowc = min(rowg, N_NODES - 1);

    f32x4 acc[8];
#pragma unroll
    for (int t = 0; t < 8; ++t) acc[t] = (f32x4){0.f, 0.f, 0.f, 0.f};

    for (int ks = 0; ks < 8; ++ks) {
        const int kc = ks * 32;
        const int kcol = kc & 127;
        const unsigned short* sH = (kc < 128) ? aggH : hH;
        const unsigned short* sL = (kc < 128) ? aggL : hL;
        // A fragments: issue before staging so one drain covers both
        bfrag a_h = *reinterpret_cast<const bfrag*>(sH + (size_t)rowc * 128 + kcol + kg * 8);
        bfrag a_l = *reinterpret_cast<const bfrag*>(sL + (size_t)rowc * 128 + kcol + kg * 8);
        // stage W tile: wave wv stages k-chunk wv, all 128 j rows (2 loads hi + 2 lo)
        {
            const unsigned short* g0 = WH + (size_t)lane * 256 + kc + wv * 8;
            const unsigned short* g1 = WH + (size_t)(64 + lane) * 256 + kc + wv * 8;
            GLOAD16(g0, (char*)&Bh[0][0][0] + wv * 2048);
            GLOAD16(g1, (char*)&Bh[0][0][0] + wv * 2048 + 1024);
            const unsigned short* g2 = WL + (size_t)lane * 256 + kc + wv * 8;
            const unsigned short* g3 = WL + (size_t)(64 + lane) * 256 + kc + wv * 8;
            GLOAD16(g2, (char*)&Bl[0][0][0] + wv * 2048);
            GLOAD16(g3, (char*)&Bl[0][0][0] + wv * 2048 + 1024);
        }
        __syncthreads();   // compiler drains vmcnt before barrier -> LDS + A regs ready
#pragma unroll
        for (int t = 0; t < 8; ++t) {
            bfrag bh = *reinterpret_cast<const bfrag*>(&Bh[kg][t * 16 + m16][0]);
            bfrag bl = *reinterpret_cast<const bfrag*>(&Bl[kg][t * 16 + m16][0]);
            acc[t] = __builtin_amdgcn_mfma_f32_16x16x32_bf16(a_h, bh, acc[t], 0, 0, 0);
            acc[t] = __builtin_amdgcn_mfma_f32_16x16x32_bf16(a_l, bh, acc[t], 0, 0, 0);
            acc[t] = __builtin_amdgcn_mfma_f32_16x16x32_bf16(a_h, bl, acc[t], 0, 0, 0);
        }
        __syncthreads();   // protect LDS before next stage
    }

    // epilogue: C row = blockRow + wv*16 + kg*4 + r, col = t*16 + m16
#pragma unroll
    for (int t = 0; t < 8; ++t) {
        int col = t * 16 + m16;
        float bv = bias[col];
#pragma unroll
        for (int r = 0; r < 4; ++r) {
            int row = blockRow + wv * 16 + kg * 4 + r;
            if (row >= N_NODES) continue;
            float v = acc[t][r] + bv;
            if (RELU) v = fmaxf(v, 0.f);
            OutF[(size_t)row * 128 + col] = v;
            if (!LAST) {
                unsigned short hi = f2bf_rn(v);
                BH[(size_t)row * 128 + col] = hi;
                BL[(size_t)row * 128 + col] = f2bf_rn(v - bf2f(hi));
            }
        }
    }
}

extern "C" void kernel_launch(void* const* d_in, const int* in_sizes, int n_in,
                              void* d_out, int out_size, void* d_ws, size_t ws_size,
                              hipStream_t stream) {
    const float* x  = (const float*)d_in[0];
    const int*   ei = (const int*)d_in[1];
    const float* Wl = (const float*)d_in[2];
    const float* bl = (const float*)d_in[3];
    const float* Wr = (const float*)d_in[4];
    float* out = (float*)d_out;
    char* ws = (char*)d_ws;

    int*            flag     = (int*)(ws + 0);
    int*            partials = (int*)(ws + 1024);
    int*            deg      = (int*)(ws + 4096);
    int*            offs     = (int*)(ws + 204800);
    int*            cursor   = (int*)(ws + 405504);
    float*          invd     = (float*)(ws + 606208);
    int*            src      = (int*)(ws + 806912);
    int*            dst      = (int*)(ws + 4007936);
    int*            csr      = (int*)(ws + 7208960);
    unsigned short* WH       = (unsigned short*)(ws + 10409984);
    unsigned short* WL       = (unsigned short*)(ws + 10606592);
    unsigned short* aggH     = (unsigned short*)(ws + 10804224);
    unsigned short* aggL     = (unsigned short*)(ws + 23604224);
    unsigned short* p0H      = (unsigned short*)(ws + 36405248);
    unsigned short* p0L      = (unsigned short*)(ws + 49205248);
    // total ws use ~62 MB

    hipMemsetAsync(deg, 0, N_NODES * sizeof(int), stream);
    detect_dtype_kernel<<<1, 256, 0, stream>>>((const unsigned int*)ei, flag);
    convert_hist_kernel<<<(N_EDGES + 255) / 256, 256, 0, stream>>>(ei, flag, src, dst, deg);
    partial_sum_kernel<<<SCAN_NBLK, 256, 0, stream>>>(deg, partials);
    scan_partials_kernel<<<1, 256, 0, stream>>>(partials, offs);
    scan_final_kernel<<<SCAN_NBLK, 256, 0, stream>>>(deg, partials, offs, cursor, invd);
    bucket_kernel<<<(N_EDGES + 255) / 256, 256, 0, stream>>>(src, dst, cursor, csr);
    prep_w_kernel<<<(N_LAYERS * 128 * 256 + 255) / 256, 256, 0, stream>>>(Wl, Wr, WH, WL);
    split_x_kernel<<<(N_NODES * 32 + 255) / 256, 256, 0, stream>>>(x, p0H, p0L);

    const int aggGrid = N_NODES / 4;            // 12500
    const int gemmGrid = (N_NODES + 63) / 64;   // 782

    // layer 0: agg(x); C = [agg|x] @ W0 -> out(fp32) + p0(bf16 in-place)
    aggregate_kernel<<<aggGrid, 256, 0, stream>>>(x, offs, csr, invd, aggH, aggL);
    mfma_gemm_kernel<1, 0><<<gemmGrid, 256, 0, stream>>>(aggH, aggL, p0H, p0L,
        WH + 0 * 32768, WL + 0 * 32768, bl + 0, out, p0H, p0L);
    // layer 1: agg(out); C -> out + p0
    aggregate_kernel<<<aggGrid, 256, 0, stream>>>(out, offs, csr, invd, aggH, aggL);
    mfma_gemm_kernel<1, 0><<<gemmGrid, 256, 0, stream>>>(aggH, aggL, p0H, p0L,
        WH + 1 * 32768, WL + 1 * 32768, bl + 128, out, p0H, p0L);
    // layer 2: agg(out); C -> out (final, no ReLU, no bf16 out)
    aggregate_kernel<<<aggGrid, 256, 0, stream>>>(out, offs, csr, invd, aggH, aggL);
    mfma_gemm_kernel<0, 1><<<gemmGrid, 256, 0, stream>>>(aggH, aggL, p0H, p0L,
        WH + 2 * 32768, WL + 2 * 32768, bl + 256, out, nullptr, nullptr);
}

// Round 5
// 320.749 us; speedup vs baseline: 2.0734x; 1.1862x over previous
//
#include <hip/hip_runtime.h>

#define N_NODES 50000
#define N_EDGES 800000
#define D 128
#define N_LAYERS 3
#define SCAN_NBLK ((N_NODES + 255) / 256)   // 196

typedef __attribute__((ext_vector_type(8))) short bfrag;
typedef __attribute__((ext_vector_type(4))) float f32x4;
typedef __attribute__((ext_vector_type(8))) unsigned short u16x8;

__device__ __forceinline__ unsigned short f2bf_rn(float f) {
    union { float f; unsigned u; } a; a.f = f;
    unsigned r = a.u + 0x7fffu + ((a.u >> 16) & 1u);
    return (unsigned short)(r >> 16);
}
__device__ __forceinline__ float bf2f(unsigned short h) {
    union { unsigned u; float f; } a; a.u = ((unsigned)h) << 16;
    return a.f;
}
__device__ __forceinline__ unsigned short f2h(float f) {
    union { unsigned short s[1]; _Float16 h; } a; a.h = (_Float16)f; return a.s[0];
}
__device__ __forceinline__ float h2f(unsigned short u) {
    union { unsigned short s[1]; _Float16 h; } a; a.s[0] = u; return (float)a.h;
}

#define GLOAD16(g, l) __builtin_amdgcn_global_load_lds( \
    (const __attribute__((address_space(1))) void*)(g), \
    (__attribute__((address_space(3))) void*)(l), 16, 0, 0)

// ---------------- edge dtype detection (int64 vs int32) ----------------
__global__ void detect_dtype_kernel(const unsigned int* __restrict__ edge, int* __restrict__ flag) {
    __shared__ int any_nz;
    if (threadIdx.x == 0) any_nz = 0;
    __syncthreads();
    int nz = 0;
    for (int i = threadIdx.x; i < 2048; i += blockDim.x) {
        if (edge[2 * i + 1] != 0u) nz = 1;
    }
    if (nz) atomicOr(&any_nz, 1);
    __syncthreads();
    if (threadIdx.x == 0) *flag = any_nz ? 0 : 1;   // 1 => int64 layout
}

__global__ void convert_hist_kernel(const int* __restrict__ edge, const int* __restrict__ flag,
                                    int* __restrict__ src, int* __restrict__ dst,
                                    int* __restrict__ deg) {
    int i = blockIdx.x * blockDim.x + threadIdx.x;
    if (i >= N_EDGES) return;
    int s, d;
    if (*flag) {
        s = edge[2 * (size_t)i];
        d = edge[2 * ((size_t)N_EDGES + i)];
    } else {
        s = edge[i];
        d = edge[N_EDGES + i];
    }
    src[i] = s;
    dst[i] = d;
    atomicAdd(&deg[d], 1);
}

// ---------------- hierarchical exclusive scan ----------------
__global__ __launch_bounds__(256) void partial_sum_kernel(const int* __restrict__ deg,
                                                          int* __restrict__ partials) {
    __shared__ int s[256];
    int i = blockIdx.x * 256 + threadIdx.x;
    int v = (i < N_NODES) ? deg[i] : 0;
    s[threadIdx.x] = v;
    __syncthreads();
    for (int off = 128; off > 0; off >>= 1) {
        if (threadIdx.x < off) s[threadIdx.x] += s[threadIdx.x + off];
        __syncthreads();
    }
    if (threadIdx.x == 0) partials[blockIdx.x] = s[0];
}

__global__ __launch_bounds__(256) void scan_partials_kernel(int* __restrict__ partials,
                                                            int* __restrict__ offsets) {
    __shared__ int s[256];
    int t = threadIdx.x;
    int v = (t < SCAN_NBLK) ? partials[t] : 0;
    s[t] = v;
    __syncthreads();
    for (int off = 1; off < 256; off <<= 1) {
        int u = (t >= off) ? s[t - off] : 0;
        __syncthreads();
        s[t] += u;
        __syncthreads();
    }
    if (t < SCAN_NBLK) partials[t] = s[t] - v;
    if (t == 255) offsets[N_NODES] = s[255];
}

__global__ __launch_bounds__(256) void scan_final_kernel(const int* __restrict__ deg,
                                                         const int* __restrict__ partials,
                                                         int* __restrict__ offsets,
                                                         int* __restrict__ cursor,
                                                         float* __restrict__ inv_deg) {
    __shared__ int s[256];
    int t = threadIdx.x;
    int i = blockIdx.x * 256 + t;
    int v = (i < N_NODES) ? deg[i] : 0;
    s[t] = v;
    __syncthreads();
    for (int off = 1; off < 256; off <<= 1) {
        int u = (t >= off) ? s[t - off] : 0;
        __syncthreads();
        s[t] += u;
        __syncthreads();
    }
    if (i < N_NODES) {
        int excl = partials[blockIdx.x] + s[t] - v;
        offsets[i] = excl;
        cursor[i] = excl;
        inv_deg[i] = 1.0f / (float)max(v, 1);
    }
}

__global__ void bucket_kernel(const int* __restrict__ src, const int* __restrict__ dst,
                              int* __restrict__ cursor, int* __restrict__ csr_src) {
    int e = blockIdx.x * blockDim.x + threadIdx.x;
    if (e >= N_EDGES) return;
    int d = dst[e];
    int pos = atomicAdd(&cursor[d], 1);
    csr_src[pos] = src[e];
}

// ---------------- weight split: Wt[l][j][k] (k contiguous), hi/lo bf16 ----------------
__global__ void prep_w_kernel(const float* __restrict__ Wl, const float* __restrict__ Wr,
                              unsigned short* __restrict__ WH, unsigned short* __restrict__ WL) {
    int idx = blockIdx.x * blockDim.x + threadIdx.x;
    if (idx >= N_LAYERS * 128 * 256) return;
    int k = idx & 255;
    int j = (idx >> 8) & 127;
    int l = idx >> 15;
    float v = (k < 128) ? Wl[((size_t)l * 128 + j) * 128 + k]
                        : Wr[((size_t)l * 128 + j) * 128 + (k - 128)];
    unsigned short hi = f2bf_rn(v);
    WH[idx] = hi;
    WL[idx] = f2bf_rn(v - bf2f(hi));
}

// ---------------- x split: fp32 -> bf16 hi/lo + fp16 ----------------
__global__ void split_x_kernel(const float* __restrict__ x,
                               unsigned short* __restrict__ H, unsigned short* __restrict__ L,
                               unsigned short* __restrict__ F16) {
    int t = blockIdx.x * 256 + threadIdx.x;   // over N_NODES*32 float4s
    if (t >= N_NODES * 32) return;
    float4 v = reinterpret_cast<const float4*>(x)[t];
    ushort4 h, l, f;
    h.x = f2bf_rn(v.x); l.x = f2bf_rn(v.x - bf2f(h.x)); f.x = f2h(v.x);
    h.y = f2bf_rn(v.y); l.y = f2bf_rn(v.y - bf2f(h.y)); f.y = f2h(v.y);
    h.z = f2bf_rn(v.z); l.z = f2bf_rn(v.z - bf2f(h.z)); f.z = f2h(v.z);
    h.w = f2bf_rn(v.w); l.w = f2bf_rn(v.w - bf2f(h.w)); f.w = f2h(v.w);
    reinterpret_cast<ushort4*>(H)[t] = h;
    reinterpret_cast<ushort4*>(L)[t] = l;
    reinterpret_cast<ushort4*>(F16)[t] = f;
}

// ---------------- mean aggregation: fp16 input rows (256B), 4 quarter-waves ----------------
// quarter q (16 lanes x ushort8 = 256B) covers one edge row; unroll x2 ->
// 8 independent row-gathers in flight per wave. f32 accumulate, bf16 hi/lo out.
__global__ __launch_bounds__(256) void aggregate_kernel(const unsigned short* __restrict__ hF16,
                                                        const int* __restrict__ offsets,
                                                        const int* __restrict__ csr_src,
                                                        const float* __restrict__ inv_deg,
                                                        unsigned short* __restrict__ aggH,
                                                        unsigned short* __restrict__ aggL) {
    int node = blockIdx.x * 4 + (threadIdx.x >> 6);
    int lane = threadIdx.x & 63;
    int q = lane >> 4;       // 0..3
    int c = lane & 15;       // covers fp16 elems c*8..c*8+7
    if (node >= N_NODES) return;
    int beg = offsets[node];
    int end = offsets[node + 1];
    float a0[8], a1[8];
#pragma unroll
    for (int j = 0; j < 8; ++j) { a0[j] = 0.f; a1[j] = 0.f; }
    int e = beg + q;
    for (; e + 4 < end; e += 8) {
        int s0 = csr_src[e];
        int s1 = csr_src[e + 4];
        u16x8 v0 = *reinterpret_cast<const u16x8*>(hF16 + (size_t)s0 * 128 + c * 8);
        u16x8 v1 = *reinterpret_cast<const u16x8*>(hF16 + (size_t)s1 * 128 + c * 8);
#pragma unroll
        for (int j = 0; j < 8; ++j) {
            a0[j] += h2f(v0[j]);
            a1[j] += h2f(v1[j]);
        }
    }
    if (e < end) {
        int s0 = csr_src[e];
        u16x8 v0 = *reinterpret_cast<const u16x8*>(hF16 + (size_t)s0 * 128 + c * 8);
#pragma unroll
        for (int j = 0; j < 8; ++j) a0[j] += h2f(v0[j]);
    }
#pragma unroll
    for (int j = 0; j < 8; ++j) a0[j] += a1[j];
#pragma unroll
    for (int j = 0; j < 8; ++j) a0[j] += __shfl_xor(a0[j], 16, 64);
#pragma unroll
    for (int j = 0; j < 8; ++j) a0[j] += __shfl_xor(a0[j], 32, 64);
    if (q == 0) {
        float w = inv_deg[node];
        u16x8 hi, lo;
#pragma unroll
        for (int j = 0; j < 8; ++j) {
            float v = a0[j] * w;
            hi[j] = f2bf_rn(v);
            lo[j] = f2bf_rn(v - bf2f(hi[j]));
        }
        *reinterpret_cast<u16x8*>(aggH + (size_t)node * 128 + c * 8) = hi;
        *reinterpret_cast<u16x8*>(aggL + (size_t)node * 128 + c * 8) = lo;
    }
}

// ---------------- MFMA GEMM: C = [agg|h] @ Wt^T + bias, split-bf16 3-term ----------------
// Non-LAST: emit fp16 h (for next aggregate) + bf16 hi/lo (for next GEMM A).
// LAST: emit fp32 into d_out only.
template <int RELU, int LAST>
__global__ __launch_bounds__(256) void mfma_gemm_kernel(
    const unsigned short* __restrict__ aggH, const unsigned short* __restrict__ aggL,
    const unsigned short* hH, const unsigned short* hL,
    const unsigned short* __restrict__ WH, const unsigned short* __restrict__ WL,
    const float* __restrict__ bias,
    float* __restrict__ OutF, unsigned short* H16, unsigned short* BH, unsigned short* BL)
{
    __shared__ __align__(16) unsigned short Bh[4][128][8];
    __shared__ __align__(16) unsigned short Bl[4][128][8];
    const int tid = threadIdx.x;
    const int lane = tid & 63;
    const int wv = tid >> 6;           // 0..3
    const int m16 = lane & 15;
    const int kg = lane >> 4;          // 0..3
    const int blockRow = blockIdx.x * 64;
    const int rowg = blockRow + wv * 16 + m16;
    const int rowc = min(rowg, N_NODES - 1);

    f32x4 acc[8];
#pragma unroll
    for (int t = 0; t < 8; ++t) acc[t] = (f32x4){0.f, 0.f, 0.f, 0.f};

    for (int ks = 0; ks < 8; ++ks) {
        const int kc = ks * 32;
        const int kcol = kc & 127;
        const unsigned short* sH = (kc < 128) ? aggH : hH;
        const unsigned short* sL = (kc < 128) ? aggL : hL;
        bfrag a_h = *reinterpret_cast<const bfrag*>(sH + (size_t)rowc * 128 + kcol + kg * 8);
        bfrag a_l = *reinterpret_cast<const bfrag*>(sL + (size_t)rowc * 128 + kcol + kg * 8);
        {
            const unsigned short* g0 = WH + (size_t)lane * 256 + kc + wv * 8;
            const unsigned short* g1 = WH + (size_t)(64 + lane) * 256 + kc + wv * 8;
            GLOAD16(g0, (char*)&Bh[0][0][0] + wv * 2048);
            GLOAD16(g1, (char*)&Bh[0][0][0] + wv * 2048 + 1024);
            const unsigned short* g2 = WL + (size_t)lane * 256 + kc + wv * 8;
            const unsigned short* g3 = WL + (size_t)(64 + lane) * 256 + kc + wv * 8;
            GLOAD16(g2, (char*)&Bl[0][0][0] + wv * 2048);
            GLOAD16(g3, (char*)&Bl[0][0][0] + wv * 2048 + 1024);
        }
        __syncthreads();
#pragma unroll
        for (int t = 0; t < 8; ++t) {
            bfrag bh = *reinterpret_cast<const bfrag*>(&Bh[kg][t * 16 + m16][0]);
            bfrag bl = *reinterpret_cast<const bfrag*>(&Bl[kg][t * 16 + m16][0]);
            acc[t] = __builtin_amdgcn_mfma_f32_16x16x32_bf16(a_h, bh, acc[t], 0, 0, 0);
            acc[t] = __builtin_amdgcn_mfma_f32_16x16x32_bf16(a_l, bh, acc[t], 0, 0, 0);
            acc[t] = __builtin_amdgcn_mfma_f32_16x16x32_bf16(a_h, bl, acc[t], 0, 0, 0);
        }
        __syncthreads();
    }

#pragma unroll
    for (int t = 0; t < 8; ++t) {
        int col = t * 16 + m16;
        float bv = bias[col];
#pragma unroll
        for (int r = 0; r < 4; ++r) {
            int row = blockRow + wv * 16 + kg * 4 + r;
            if (row >= N_NODES) continue;
            float v = acc[t][r] + bv;
            if (RELU) v = fmaxf(v, 0.f);
            if (LAST) {
                OutF[(size_t)row * 128 + col] = v;
            } else {
                H16[(size_t)row * 128 + col] = f2h(v);
                unsigned short hi = f2bf_rn(v);
                BH[(size_t)row * 128 + col] = hi;
                BL[(size_t)row * 128 + col] = f2bf_rn(v - bf2f(hi));
            }
        }
    }
}

extern "C" void kernel_launch(void* const* d_in, const int* in_sizes, int n_in,
                              void* d_out, int out_size, void* d_ws, size_t ws_size,
                              hipStream_t stream) {
    const float* x  = (const float*)d_in[0];
    const int*   ei = (const int*)d_in[1];
    const float* Wl = (const float*)d_in[2];
    const float* bl = (const float*)d_in[3];
    const float* Wr = (const float*)d_in[4];
    float* out = (float*)d_out;
    unsigned short* h16 = (unsigned short*)d_out;   // fp16 scratch inside d_out (12.8 of 25.6 MB);
                                                    // last read: aggregate L2, then gemm L2 overwrites
    char* ws = (char*)d_ws;

    int*            flag     = (int*)(ws + 0);
    int*            partials = (int*)(ws + 1024);
    int*            deg      = (int*)(ws + 4096);
    int*            offs     = (int*)(ws + 204800);
    int*            cursor   = (int*)(ws + 405504);
    float*          invd     = (float*)(ws + 606208);
    int*            src      = (int*)(ws + 806912);
    int*            dst      = (int*)(ws + 4007936);
    int*            csr      = (int*)(ws + 7208960);
    unsigned short* WH       = (unsigned short*)(ws + 10409984);
    unsigned short* WL       = (unsigned short*)(ws + 10606592);
    unsigned short* aggH     = (unsigned short*)(ws + 10804224);
    unsigned short* aggL     = (unsigned short*)(ws + 23604224);
    unsigned short* pH       = (unsigned short*)(ws + 36405248);
    unsigned short* pL       = (unsigned short*)(ws + 49205248);
    // total ws use ~62 MB (same as proven layout)

    hipMemsetAsync(deg, 0, N_NODES * sizeof(int), stream);
    detect_dtype_kernel<<<1, 256, 0, stream>>>((const unsigned int*)ei, flag);
    convert_hist_kernel<<<(N_EDGES + 255) / 256, 256, 0, stream>>>(ei, flag, src, dst, deg);
    partial_sum_kernel<<<SCAN_NBLK, 256, 0, stream>>>(deg, partials);
    scan_partials_kernel<<<1, 256, 0, stream>>>(partials, offs);
    scan_final_kernel<<<SCAN_NBLK, 256, 0, stream>>>(deg, partials, offs, cursor, invd);
    bucket_kernel<<<(N_EDGES + 255) / 256, 256, 0, stream>>>(src, dst, cursor, csr);
    prep_w_kernel<<<(N_LAYERS * 128 * 256 + 255) / 256, 256, 0, stream>>>(Wl, Wr, WH, WL);
    split_x_kernel<<<(N_NODES * 32 + 255) / 256, 256, 0, stream>>>(x, pH, pL, h16);

    const int aggGrid = N_NODES / 4;            // 12500
    const int gemmGrid = (N_NODES + 63) / 64;   // 782

    // layer 0: agg(x_f16); C = [agg|x] @ W0 -> h16/pH/pL (in-place over x splits)
    aggregate_kernel<<<aggGrid, 256, 0, stream>>>(h16, offs, csr, invd, aggH, aggL);
    mfma_gemm_kernel<1, 0><<<gemmGrid, 256, 0, stream>>>(aggH, aggL, pH, pL,
        WH + 0 * 32768, WL + 0 * 32768, bl + 0, nullptr, h16, pH, pL);
    // layer 1
    aggregate_kernel<<<aggGrid, 256, 0, stream>>>(h16, offs, csr, invd, aggH, aggL);
    mfma_gemm_kernel<1, 0><<<gemmGrid, 256, 0, stream>>>(aggH, aggL, pH, pL,
        WH + 1 * 32768, WL + 1 * 32768, bl + 128, nullptr, h16, pH, pL);
    // layer 2: final fp32 into d_out (overwrites fp16 scratch after its last read)
    aggregate_kernel<<<aggGrid, 256, 0, stream>>>(h16, offs, csr, invd, aggH, aggL);
    mfma_gemm_kernel<0, 1><<<gemmGrid, 256, 0, stream>>>(aggH, aggL, pH, pL,
        WH + 2 * 32768, WL + 2 * 32768, bl + 256, out, nullptr, nullptr, nullptr);
}

// Round 6
// 291.675 us; speedup vs baseline: 2.2801x; 1.0997x over previous
//
#include <hip/hip_runtime.h>

#define N_NODES 50000
#define N_EDGES 800000
#define D 128
#define N_LAYERS 3
#define SCAN_NBLK ((N_NODES + 255) / 256)   // 196
#define NBUCK ((N_NODES + 255) / 256)       // 196 coarse buckets (256 nodes each)

typedef __attribute__((ext_vector_type(8))) short bfrag;
typedef __attribute__((ext_vector_type(4))) float f32x4;
typedef __attribute__((ext_vector_type(8))) unsigned short u16x8;

__device__ __forceinline__ unsigned short f2bf_rn(float f) {
    union { float f; unsigned u; } a; a.f = f;
    unsigned r = a.u + 0x7fffu + ((a.u >> 16) & 1u);
    return (unsigned short)(r >> 16);
}
__device__ __forceinline__ float bf2f(unsigned short h) {
    union { unsigned u; float f; } a; a.u = ((unsigned)h) << 16;
    return a.f;
}
__device__ __forceinline__ unsigned short f2h(float f) {
    union { unsigned short s[1]; _Float16 h; } a; a.h = (_Float16)f; return a.s[0];
}
__device__ __forceinline__ float h2f(unsigned short u) {
    union { unsigned short s[1]; _Float16 h; } a; a.s[0] = u; return (float)a.h;
}

#define GLOAD16(g, l) __builtin_amdgcn_global_load_lds( \
    (const __attribute__((address_space(1))) void*)(g), \
    (__attribute__((address_space(3))) void*)(l), 16, 0, 0)

// ---------------- edge dtype detection (int64 vs int32) ----------------
__global__ void detect_dtype_kernel(const unsigned int* __restrict__ edge, int* __restrict__ flag) {
    __shared__ int any_nz;
    if (threadIdx.x == 0) any_nz = 0;
    __syncthreads();
    int nz = 0;
    for (int i = threadIdx.x; i < 2048; i += blockDim.x) {
        if (edge[2 * i + 1] != 0u) nz = 1;
    }
    if (nz) atomicOr(&any_nz, 1);
    __syncthreads();
    if (threadIdx.x == 0) *flag = any_nz ? 0 : 1;   // 1 => int64 layout
}

__global__ void convert_hist_kernel(const int* __restrict__ edge, const int* __restrict__ flag,
                                    int* __restrict__ src, int* __restrict__ dst,
                                    int* __restrict__ deg) {
    int i = blockIdx.x * blockDim.x + threadIdx.x;
    if (i >= N_EDGES) return;
    int s, d;
    if (*flag) {
        s = edge[2 * (size_t)i];
        d = edge[2 * ((size_t)N_EDGES + i)];
    } else {
        s = edge[i];
        d = edge[N_EDGES + i];
    }
    src[i] = s;
    dst[i] = d;
    atomicAdd(&deg[d], 1);
}

// ---------------- hierarchical exclusive scan ----------------
__global__ __launch_bounds__(256) void partial_sum_kernel(const int* __restrict__ deg,
                                                          int* __restrict__ partials) {
    __shared__ int s[256];
    int i = blockIdx.x * 256 + threadIdx.x;
    int v = (i < N_NODES) ? deg[i] : 0;
    s[threadIdx.x] = v;
    __syncthreads();
    for (int off = 128; off > 0; off >>= 1) {
        if (threadIdx.x < off) s[threadIdx.x] += s[threadIdx.x + off];
        __syncthreads();
    }
    if (threadIdx.x == 0) partials[blockIdx.x] = s[0];
}

__global__ __launch_bounds__(256) void scan_partials_kernel(int* __restrict__ partials,
                                                            int* __restrict__ offsets) {
    __shared__ int s[256];
    int t = threadIdx.x;
    int v = (t < SCAN_NBLK) ? partials[t] : 0;
    s[t] = v;
    __syncthreads();
    for (int off = 1; off < 256; off <<= 1) {
        int u = (t >= off) ? s[t - off] : 0;
        __syncthreads();
        s[t] += u;
        __syncthreads();
    }
    if (t < SCAN_NBLK) partials[t] = s[t] - v;
    if (t == 255) offsets[N_NODES] = s[255];
}

__global__ __launch_bounds__(256) void scan_final_kernel(const int* __restrict__ deg,
                                                         const int* __restrict__ partials,
                                                         int* __restrict__ offsets,
                                                         int* __restrict__ cursor1,
                                                         float* __restrict__ inv_deg) {
    __shared__ int s[256];
    int t = threadIdx.x;
    int i = blockIdx.x * 256 + t;
    int v = (i < N_NODES) ? deg[i] : 0;
    s[t] = v;
    __syncthreads();
    for (int off = 1; off < 256; off <<= 1) {
        int u = (t >= off) ? s[t - off] : 0;
        __syncthreads();
        s[t] += u;
        __syncthreads();
    }
    if (i < N_NODES) {
        int excl = partials[blockIdx.x] + s[t] - v;
        offsets[i] = excl;
        inv_deg[i] = 1.0f / (float)max(v, 1);
        if ((i & 255) == 0) cursor1[i >> 8] = excl;   // coarse bucket base
    }
}

// ---------------- pass 1: coarse bucket scatter (LDS-staged counting sort) ----------------
// 4096 edges/block; 196 buckets of 256 nodes. Packed entry: (dstLocal<<18)|src.
__global__ __launch_bounds__(256) void pass1_kernel(const int* __restrict__ src,
                                                    const int* __restrict__ dst,
                                                    int* __restrict__ cursor1,
                                                    int* __restrict__ packed) {
    __shared__ int hist[NBUCK];
    __shared__ int base[NBUCK];
    const int t = threadIdx.x;
    const int blockBeg = blockIdx.x * 4096;
    for (int i = t; i < NBUCK; i += 256) hist[i] = 0;
    __syncthreads();
    int es[16], ed[16];
#pragma unroll
    for (int j = 0; j < 16; ++j) {
        int e = blockBeg + j * 256 + t;   // coalesced
        if (e < N_EDGES) { es[j] = src[e]; ed[j] = dst[e]; }
        else ed[j] = -1;
    }
#pragma unroll
    for (int j = 0; j < 16; ++j)
        if (ed[j] >= 0) atomicAdd(&hist[ed[j] >> 8], 1);
    __syncthreads();
    for (int i = t; i < NBUCK; i += 256) {
        base[i] = atomicAdd(&cursor1[i], hist[i]);
        hist[i] = 0;                       // reuse as within-block cursor
    }
    __syncthreads();
#pragma unroll
    for (int j = 0; j < 16; ++j) {
        if (ed[j] >= 0) {
            int b = ed[j] >> 8;
            int pos = base[b] + atomicAdd(&hist[b], 1);
            packed[pos] = ((ed[j] & 255) << 18) | es[j];
        }
    }
}

// ---------------- pass 2: within-bucket sort (per-node LDS cursors) ----------------
__global__ __launch_bounds__(256) void pass2_kernel(const int* __restrict__ offsets,
                                                    const int* __restrict__ packed,
                                                    int* __restrict__ csr) {
    __shared__ int cur[256];
    const int t = threadIdx.x;
    const int nodeBeg = blockIdx.x * 256;
    int node = nodeBeg + t;
    cur[t] = (node < N_NODES) ? offsets[node] : 0;
    __syncthreads();
    int beg = offsets[nodeBeg];
    int end = offsets[min(nodeBeg + 256, N_NODES)];
    for (int e = beg + t; e < end; e += 256) {
        int p = packed[e];
        int pos = atomicAdd(&cur[p >> 18], 1);
        csr[pos] = p & 0x3FFFF;
    }
}

// ---------------- weight split: Wt[l][j][k] (k contiguous), hi/lo bf16 ----------------
__global__ void prep_w_kernel(const float* __restrict__ Wl, const float* __restrict__ Wr,
                              unsigned short* __restrict__ WH, unsigned short* __restrict__ WL) {
    int idx = blockIdx.x * blockDim.x + threadIdx.x;
    if (idx >= N_LAYERS * 128 * 256) return;
    int k = idx & 255;
    int j = (idx >> 8) & 127;
    int l = idx >> 15;
    float v = (k < 128) ? Wl[((size_t)l * 128 + j) * 128 + k]
                        : Wr[((size_t)l * 128 + j) * 128 + (k - 128)];
    unsigned short hi = f2bf_rn(v);
    WH[idx] = hi;
    WL[idx] = f2bf_rn(v - bf2f(hi));
}

// ---------------- x split: fp32 -> bf16 hi/lo + fp16 ----------------
__global__ void split_x_kernel(const float* __restrict__ x,
                               unsigned short* __restrict__ H, unsigned short* __restrict__ L,
                               unsigned short* __restrict__ F16) {
    int t = blockIdx.x * 256 + threadIdx.x;   // over N_NODES*32 float4s
    if (t >= N_NODES * 32) return;
    float4 v = reinterpret_cast<const float4*>(x)[t];
    ushort4 h, l, f;
    h.x = f2bf_rn(v.x); l.x = f2bf_rn(v.x - bf2f(h.x)); f.x = f2h(v.x);
    h.y = f2bf_rn(v.y); l.y = f2bf_rn(v.y - bf2f(h.y)); f.y = f2h(v.y);
    h.z = f2bf_rn(v.z); l.z = f2bf_rn(v.z - bf2f(h.z)); f.z = f2h(v.z);
    h.w = f2bf_rn(v.w); l.w = f2bf_rn(v.w - bf2f(h.w)); f.w = f2h(v.w);
    reinterpret_cast<ushort4*>(H)[t] = h;
    reinterpret_cast<ushort4*>(L)[t] = l;
    reinterpret_cast<ushort4*>(F16)[t] = f;
}

// ---------------- mean aggregation: fp16 input rows (256B), 4 quarter-waves ----------------
__global__ __launch_bounds__(256) void aggregate_kernel(const unsigned short* __restrict__ hF16,
                                                        const int* __restrict__ offsets,
                                                        const int* __restrict__ csr_src,
                                                        const float* __restrict__ inv_deg,
                                                        unsigned short* __restrict__ aggH,
                                                        unsigned short* __restrict__ aggL) {
    int node = blockIdx.x * 4 + (threadIdx.x >> 6);
    int lane = threadIdx.x & 63;
    int q = lane >> 4;       // 0..3
    int c = lane & 15;       // covers fp16 elems c*8..c*8+7
    if (node >= N_NODES) return;
    int beg = offsets[node];
    int end = offsets[node + 1];
    float a0[8], a1[8];
#pragma unroll
    for (int j = 0; j < 8; ++j) { a0[j] = 0.f; a1[j] = 0.f; }
    int e = beg + q;
    for (; e + 4 < end; e += 8) {
        int s0 = csr_src[e];
        int s1 = csr_src[e + 4];
        u16x8 v0 = *reinterpret_cast<const u16x8*>(hF16 + (size_t)s0 * 128 + c * 8);
        u16x8 v1 = *reinterpret_cast<const u16x8*>(hF16 + (size_t)s1 * 128 + c * 8);
#pragma unroll
        for (int j = 0; j < 8; ++j) {
            a0[j] += h2f(v0[j]);
            a1[j] += h2f(v1[j]);
        }
    }
    if (e < end) {
        int s0 = csr_src[e];
        u16x8 v0 = *reinterpret_cast<const u16x8*>(hF16 + (size_t)s0 * 128 + c * 8);
#pragma unroll
        for (int j = 0; j < 8; ++j) a0[j] += h2f(v0[j]);
    }
#pragma unroll
    for (int j = 0; j < 8; ++j) a0[j] += a1[j];
#pragma unroll
    for (int j = 0; j < 8; ++j) a0[j] += __shfl_xor(a0[j], 16, 64);
#pragma unroll
    for (int j = 0; j < 8; ++j) a0[j] += __shfl_xor(a0[j], 32, 64);
    if (q == 0) {
        float w = inv_deg[node];
        u16x8 hi, lo;
#pragma unroll
        for (int j = 0; j < 8; ++j) {
            float v = a0[j] * w;
            hi[j] = f2bf_rn(v);
            lo[j] = f2bf_rn(v - bf2f(hi[j]));
        }
        *reinterpret_cast<u16x8*>(aggH + (size_t)node * 128 + c * 8) = hi;
        *reinterpret_cast<u16x8*>(aggL + (size_t)node * 128 + c * 8) = lo;
    }
}

// ---------------- MFMA GEMM: C = [agg|h] @ Wt^T + bias, split-bf16 3-term ----------------
template <int RELU, int LAST>
__global__ __launch_bounds__(256) void mfma_gemm_kernel(
    const unsigned short* __restrict__ aggH, const unsigned short* __restrict__ aggL,
    const unsigned short* hH, const unsigned short* hL,
    const unsigned short* __restrict__ WH, const unsigned short* __restrict__ WL,
    const float* __restrict__ bias,
    float* __restrict__ OutF, unsigned short* H16, unsigned short* BH, unsigned short* BL)
{
    __shared__ __align__(16) unsigned short Bh[4][128][8];
    __shared__ __align__(16) unsigned short Bl[4][128][8];
    const int tid = threadIdx.x;
    const int lane = tid & 63;
    const int wv = tid >> 6;           // 0..3
    const int m16 = lane & 15;
    const int kg = lane >> 4;          // 0..3
    const int blockRow = blockIdx.x * 64;
    const int rowg = blockRow + wv * 16 + m16;
    const int rowc = min(rowg, N_NODES - 1);

    f32x4 acc[8];
#pragma unroll
    for (int t = 0; t < 8; ++t) acc[t] = (f32x4){0.f, 0.f, 0.f, 0.f};

    for (int ks = 0; ks < 8; ++ks) {
        const int kc = ks * 32;
        const int kcol = kc & 127;
        const unsigned short* sH = (kc < 128) ? aggH : hH;
        const unsigned short* sL = (kc < 128) ? aggL : hL;
        bfrag a_h = *reinterpret_cast<const bfrag*>(sH + (size_t)rowc * 128 + kcol + kg * 8);
        bfrag a_l = *reinterpret_cast<const bfrag*>(sL + (size_t)rowc * 128 + kcol + kg * 8);
        {
            const unsigned short* g0 = WH + (size_t)lane * 256 + kc + wv * 8;
            const unsigned short* g1 = WH + (size_t)(64 + lane) * 256 + kc + wv * 8;
            GLOAD16(g0, (char*)&Bh[0][0][0] + wv * 2048);
            GLOAD16(g1, (char*)&Bh[0][0][0] + wv * 2048 + 1024);
            const unsigned short* g2 = WL + (size_t)lane * 256 + kc + wv * 8;
            const unsigned short* g3 = WL + (size_t)(64 + lane) * 256 + kc + wv * 8;
            GLOAD16(g2, (char*)&Bl[0][0][0] + wv * 2048);
            GLOAD16(g3, (char*)&Bl[0][0][0] + wv * 2048 + 1024);
        }
        __syncthreads();
#pragma unroll
        for (int t = 0; t < 8; ++t) {
            bfrag bh = *reinterpret_cast<const bfrag*>(&Bh[kg][t * 16 + m16][0]);
            bfrag bl = *reinterpret_cast<const bfrag*>(&Bl[kg][t * 16 + m16][0]);
            acc[t] = __builtin_amdgcn_mfma_f32_16x16x32_bf16(a_h, bh, acc[t], 0, 0, 0);
            acc[t] = __builtin_amdgcn_mfma_f32_16x16x32_bf16(a_l, bh, acc[t], 0, 0, 0);
            acc[t] = __builtin_amdgcn_mfma_f32_16x16x32_bf16(a_h, bl, acc[t], 0, 0, 0);
        }
        __syncthreads();
    }

#pragma unroll
    for (int t = 0; t < 8; ++t) {
        int col = t * 16 + m16;
        float bv = bias[col];
#pragma unroll
        for (int r = 0; r < 4; ++r) {
            int row = blockRow + wv * 16 + kg * 4 + r;
            if (row >= N_NODES) continue;
            float v = acc[t][r] + bv;
            if (RELU) v = fmaxf(v, 0.f);
            if (LAST) {
                OutF[(size_t)row * 128 + col] = v;
            } else {
                H16[(size_t)row * 128 + col] = f2h(v);
                unsigned short hi = f2bf_rn(v);
                BH[(size_t)row * 128 + col] = hi;
                BL[(size_t)row * 128 + col] = f2bf_rn(v - bf2f(hi));
            }
        }
    }
}

extern "C" void kernel_launch(void* const* d_in, const int* in_sizes, int n_in,
                              void* d_out, int out_size, void* d_ws, size_t ws_size,
                              hipStream_t stream) {
    const float* x  = (const float*)d_in[0];
    const int*   ei = (const int*)d_in[1];
    const float* Wl = (const float*)d_in[2];
    const float* bl = (const float*)d_in[3];
    const float* Wr = (const float*)d_in[4];
    float* out = (float*)d_out;
    unsigned short* h16 = (unsigned short*)d_out;   // fp16 scratch inside d_out (12.8 of 25.6 MB)
    char* ws = (char*)d_ws;

    int*            flag     = (int*)(ws + 0);
    int*            partials = (int*)(ws + 1024);
    int*            deg      = (int*)(ws + 4096);
    int*            offs     = (int*)(ws + 204800);
    int*            cursor1  = (int*)(ws + 405504);
    float*          invd     = (float*)(ws + 606208);
    int*            src      = (int*)(ws + 806912);
    int*            dst      = (int*)(ws + 4007936);
    int*            csr      = (int*)(ws + 7208960);
    unsigned short* WH       = (unsigned short*)(ws + 10409984);
    unsigned short* WL       = (unsigned short*)(ws + 10606592);
    unsigned short* aggH     = (unsigned short*)(ws + 10804224);
    unsigned short* aggL     = (unsigned short*)(ws + 23604224);
    unsigned short* pH       = (unsigned short*)(ws + 36405248);
    unsigned short* pL       = (unsigned short*)(ws + 49205248);
    int*            packed   = (int*)aggH;          // 3.2 MB, dead before first aggregate write

    hipMemsetAsync(deg, 0, N_NODES * sizeof(int), stream);
    detect_dtype_kernel<<<1, 256, 0, stream>>>((const unsigned int*)ei, flag);
    convert_hist_kernel<<<(N_EDGES + 255) / 256, 256, 0, stream>>>(ei, flag, src, dst, deg);
    partial_sum_kernel<<<SCAN_NBLK, 256, 0, stream>>>(deg, partials);
    scan_partials_kernel<<<1, 256, 0, stream>>>(partials, offs);
    scan_final_kernel<<<SCAN_NBLK, 256, 0, stream>>>(deg, partials, offs, cursor1, invd);
    pass1_kernel<<<(N_EDGES + 4095) / 4096, 256, 0, stream>>>(src, dst, cursor1, packed);
    pass2_kernel<<<NBUCK, 256, 0, stream>>>(offs, packed, csr);
    prep_w_kernel<<<(N_LAYERS * 128 * 256 + 255) / 256, 256, 0, stream>>>(Wl, Wr, WH, WL);
    split_x_kernel<<<(N_NODES * 32 + 255) / 256, 256, 0, stream>>>(x, pH, pL, h16);

    const int aggGrid = N_NODES / 4;            // 12500
    const int gemmGrid = (N_NODES + 63) / 64;   // 782

    // layer 0: agg(x_f16); C = [agg|x] @ W0 -> h16/pH/pL (in-place over x splits)
    aggregate_kernel<<<aggGrid, 256, 0, stream>>>(h16, offs, csr, invd, aggH, aggL);
    mfma_gemm_kernel<1, 0><<<gemmGrid, 256, 0, stream>>>(aggH, aggL, pH, pL,
        WH + 0 * 32768, WL + 0 * 32768, bl + 0, nullptr, h16, pH, pL);
    // layer 1
    aggregate_kernel<<<aggGrid, 256, 0, stream>>>(h16, offs, csr, invd, aggH, aggL);
    mfma_gemm_kernel<1, 0><<<gemmGrid, 256, 0, stream>>>(aggH, aggL, pH, pL,
        WH + 1 * 32768, WL + 1 * 32768, bl + 128, nullptr, h16, pH, pL);
    // layer 2: final fp32 into d_out (overwrites fp16 scratch after its last read)
    aggregate_kernel<<<aggGrid, 256, 0, stream>>>(h16, offs, csr, invd, aggH, aggL);
    mfma_gemm_kernel<0, 1><<<gemmGrid, 256, 0, stream>>>(aggH, aggL, pH, pL,
        WH + 2 * 32768, WL + 2 * 32768, bl + 256, out, nullptr, nullptr, nullptr);
}

// Round 7
// 284.698 us; speedup vs baseline: 2.3360x; 1.0245x over previous
//
#include <hip/hip_runtime.h>

#define N_NODES 50000
#define N_EDGES 800000
#define D 128
#define N_LAYERS 3
#define SCAN_NBLK ((N_NODES + 255) / 256)   // 196
#define NBUCK ((N_NODES + 255) / 256)       // 196 coarse buckets (256 nodes each)

typedef __attribute__((ext_vector_type(8))) short bfrag;
typedef __attribute__((ext_vector_type(4))) float f32x4;
typedef __attribute__((ext_vector_type(8))) unsigned short u16x8;

__device__ __forceinline__ unsigned short f2bf_rn(float f) {
    union { float f; unsigned u; } a; a.f = f;
    unsigned r = a.u + 0x7fffu + ((a.u >> 16) & 1u);
    return (unsigned short)(r >> 16);
}
__device__ __forceinline__ float bf2f(unsigned short h) {
    union { unsigned u; float f; } a; a.u = ((unsigned)h) << 16;
    return a.f;
}
__device__ __forceinline__ unsigned short f2h(float f) {
    union { unsigned short s[1]; _Float16 h; } a; a.h = (_Float16)f; return a.s[0];
}
__device__ __forceinline__ float h2f(unsigned short u) {
    union { unsigned short s[1]; _Float16 h; } a; a.s[0] = u; return (float)a.h;
}

#define GLOAD16(g, l) __builtin_amdgcn_global_load_lds( \
    (const __attribute__((address_space(1))) void*)(g), \
    (__attribute__((address_space(3))) void*)(l), 16, 0, 0)

// ---------------- zero deg (runtime fill kernel is ~41us for 200KB!) ----------------
__global__ void zero_deg_kernel(int* __restrict__ deg) {
    int i = blockIdx.x * 256 + threadIdx.x;
    if (i < N_NODES) deg[i] = 0;
}

// ---------------- edge dtype detection (int64 vs int32) ----------------
__global__ void detect_dtype_kernel(const unsigned int* __restrict__ edge, int* __restrict__ flag) {
    __shared__ int any_nz;
    if (threadIdx.x == 0) any_nz = 0;
    __syncthreads();
    int nz = 0;
    for (int i = threadIdx.x; i < 2048; i += blockDim.x) {
        if (edge[2 * i + 1] != 0u) nz = 1;
    }
    if (nz) atomicOr(&any_nz, 1);
    __syncthreads();
    if (threadIdx.x == 0) *flag = any_nz ? 0 : 1;   // 1 => int64 layout
}

__global__ void convert_hist_kernel(const int* __restrict__ edge, const int* __restrict__ flag,
                                    int* __restrict__ src, int* __restrict__ dst,
                                    int* __restrict__ deg) {
    int i = blockIdx.x * blockDim.x + threadIdx.x;
    if (i >= N_EDGES) return;
    int s, d;
    if (*flag) {
        s = edge[2 * (size_t)i];
        d = edge[2 * ((size_t)N_EDGES + i)];
    } else {
        s = edge[i];
        d = edge[N_EDGES + i];
    }
    src[i] = s;
    dst[i] = d;
    atomicAdd(&deg[d], 1);
}

// ---------------- hierarchical exclusive scan ----------------
__global__ __launch_bounds__(256) void partial_sum_kernel(const int* __restrict__ deg,
                                                          int* __restrict__ partials) {
    __shared__ int s[256];
    int i = blockIdx.x * 256 + threadIdx.x;
    int v = (i < N_NODES) ? deg[i] : 0;
    s[threadIdx.x] = v;
    __syncthreads();
    for (int off = 128; off > 0; off >>= 1) {
        if (threadIdx.x < off) s[threadIdx.x] += s[threadIdx.x + off];
        __syncthreads();
    }
    if (threadIdx.x == 0) partials[blockIdx.x] = s[0];
}

__global__ __launch_bounds__(256) void scan_partials_kernel(int* __restrict__ partials,
                                                            int* __restrict__ offsets) {
    __shared__ int s[256];
    int t = threadIdx.x;
    int v = (t < SCAN_NBLK) ? partials[t] : 0;
    s[t] = v;
    __syncthreads();
    for (int off = 1; off < 256; off <<= 1) {
        int u = (t >= off) ? s[t - off] : 0;
        __syncthreads();
        s[t] += u;
        __syncthreads();
    }
    if (t < SCAN_NBLK) partials[t] = s[t] - v;
    if (t == 255) offsets[N_NODES] = s[255];
}

__global__ __launch_bounds__(256) void scan_final_kernel(const int* __restrict__ deg,
                                                         const int* __restrict__ partials,
                                                         int* __restrict__ offsets,
                                                         int* __restrict__ cursor1,
                                                         float* __restrict__ inv_deg) {
    __shared__ int s[256];
    int t = threadIdx.x;
    int i = blockIdx.x * 256 + t;
    int v = (i < N_NODES) ? deg[i] : 0;
    s[t] = v;
    __syncthreads();
    for (int off = 1; off < 256; off <<= 1) {
        int u = (t >= off) ? s[t - off] : 0;
        __syncthreads();
        s[t] += u;
        __syncthreads();
    }
    if (i < N_NODES) {
        int excl = partials[blockIdx.x] + s[t] - v;
        offsets[i] = excl;
        inv_deg[i] = 1.0f / (float)max(v, 1);
        if ((i & 255) == 0) cursor1[i >> 8] = excl;   // coarse bucket base
    }
}

// ---------------- pass 1: coarse bucket scatter (LDS-staged counting sort) ----------------
__global__ __launch_bounds__(256) void pass1_kernel(const int* __restrict__ src,
                                                    const int* __restrict__ dst,
                                                    int* __restrict__ cursor1,
                                                    int* __restrict__ packed) {
    __shared__ int hist[NBUCK];
    __shared__ int base[NBUCK];
    const int t = threadIdx.x;
    const int blockBeg = blockIdx.x * 4096;
    for (int i = t; i < NBUCK; i += 256) hist[i] = 0;
    __syncthreads();
    int es[16], ed[16];
#pragma unroll
    for (int j = 0; j < 16; ++j) {
        int e = blockBeg + j * 256 + t;   // coalesced
        if (e < N_EDGES) { es[j] = src[e]; ed[j] = dst[e]; }
        else ed[j] = -1;
    }
#pragma unroll
    for (int j = 0; j < 16; ++j)
        if (ed[j] >= 0) atomicAdd(&hist[ed[j] >> 8], 1);
    __syncthreads();
    for (int i = t; i < NBUCK; i += 256) {
        base[i] = atomicAdd(&cursor1[i], hist[i]);
        hist[i] = 0;                       // reuse as within-block cursor
    }
    __syncthreads();
#pragma unroll
    for (int j = 0; j < 16; ++j) {
        if (ed[j] >= 0) {
            int b = ed[j] >> 8;
            int pos = base[b] + atomicAdd(&hist[b], 1);
            packed[pos] = ((ed[j] & 255) << 18) | es[j];
        }
    }
}

// ---------------- pass 2: within-bucket sort (per-node LDS cursors) ----------------
__global__ __launch_bounds__(256) void pass2_kernel(const int* __restrict__ offsets,
                                                    const int* __restrict__ packed,
                                                    int* __restrict__ csr) {
    __shared__ int cur[256];
    const int t = threadIdx.x;
    const int nodeBeg = blockIdx.x * 256;
    int node = nodeBeg + t;
    cur[t] = (node < N_NODES) ? offsets[node] : 0;
    __syncthreads();
    int beg = offsets[nodeBeg];
    int end = offsets[min(nodeBeg + 256, N_NODES)];
    for (int e = beg + t; e < end; e += 256) {
        int p = packed[e];
        int pos = atomicAdd(&cur[p >> 18], 1);
        csr[pos] = p & 0x3FFFF;
    }
}

// ---------------- weight split: Wt[l][j][k] (k contiguous), hi/lo bf16 ----------------
__global__ void prep_w_kernel(const float* __restrict__ Wl, const float* __restrict__ Wr,
                              unsigned short* __restrict__ WH, unsigned short* __restrict__ WL) {
    int idx = blockIdx.x * blockDim.x + threadIdx.x;
    if (idx >= N_LAYERS * 128 * 256) return;
    int k = idx & 255;
    int j = (idx >> 8) & 127;
    int l = idx >> 15;
    float v = (k < 128) ? Wl[((size_t)l * 128 + j) * 128 + k]
                        : Wr[((size_t)l * 128 + j) * 128 + (k - 128)];
    unsigned short hi = f2bf_rn(v);
    WH[idx] = hi;
    WL[idx] = f2bf_rn(v - bf2f(hi));
}

// ---------------- x split: fp32 -> fp16 + fp16 residual ----------------
__global__ void split_x_kernel(const float* __restrict__ x,
                               unsigned short* __restrict__ H16, unsigned short* __restrict__ R16) {
    int t = blockIdx.x * 256 + threadIdx.x;   // over N_NODES*32 float4s
    if (t >= N_NODES * 32) return;
    float4 v = reinterpret_cast<const float4*>(x)[t];
    ushort4 h, r;
    h.x = f2h(v.x); r.x = f2h(v.x - h2f(h.x));
    h.y = f2h(v.y); r.y = f2h(v.y - h2f(h.y));
    h.z = f2h(v.z); r.z = f2h(v.z - h2f(h.z));
    h.w = f2h(v.w); r.w = f2h(v.w - h2f(h.w));
    reinterpret_cast<ushort4*>(H16)[t] = h;
    reinterpret_cast<ushort4*>(R16)[t] = r;
}

// ---------------- mean aggregation: fp16 input rows (256B), 4 quarter-waves ----------------
__global__ __launch_bounds__(256) void aggregate_kernel(const unsigned short* __restrict__ hF16,
                                                        const int* __restrict__ offsets,
                                                        const int* __restrict__ csr_src,
                                                        const float* __restrict__ inv_deg,
                                                        unsigned short* __restrict__ aggH,
                                                        unsigned short* __restrict__ aggL) {
    int node = blockIdx.x * 4 + (threadIdx.x >> 6);
    int lane = threadIdx.x & 63;
    int q = lane >> 4;       // 0..3
    int c = lane & 15;       // covers fp16 elems c*8..c*8+7
    if (node >= N_NODES) return;
    int beg = offsets[node];
    int end = offsets[node + 1];
    float a0[8], a1[8];
#pragma unroll
    for (int j = 0; j < 8; ++j) { a0[j] = 0.f; a1[j] = 0.f; }
    int e = beg + q;
    for (; e + 4 < end; e += 8) {
        int s0 = csr_src[e];
        int s1 = csr_src[e + 4];
        u16x8 v0 = *reinterpret_cast<const u16x8*>(hF16 + (size_t)s0 * 128 + c * 8);
        u16x8 v1 = *reinterpret_cast<const u16x8*>(hF16 + (size_t)s1 * 128 + c * 8);
#pragma unroll
        for (int j = 0; j < 8; ++j) {
            a0[j] += h2f(v0[j]);
            a1[j] += h2f(v1[j]);
        }
    }
    if (e < end) {
        int s0 = csr_src[e];
        u16x8 v0 = *reinterpret_cast<const u16x8*>(hF16 + (size_t)s0 * 128 + c * 8);
#pragma unroll
        for (int j = 0; j < 8; ++j) a0[j] += h2f(v0[j]);
    }
#pragma unroll
    for (int j = 0; j < 8; ++j) a0[j] += a1[j];
#pragma unroll
    for (int j = 0; j < 8; ++j) a0[j] += __shfl_xor(a0[j], 16, 64);
#pragma unroll
    for (int j = 0; j < 8; ++j) a0[j] += __shfl_xor(a0[j], 32, 64);
    if (q == 0) {
        float w = inv_deg[node];
        u16x8 hi, lo;
#pragma unroll
        for (int j = 0; j < 8; ++j) {
            float v = a0[j] * w;
            hi[j] = f2bf_rn(v);
            lo[j] = f2bf_rn(v - bf2f(hi[j]));
        }
        *reinterpret_cast<u16x8*>(aggH + (size_t)node * 128 + c * 8) = hi;
        *reinterpret_cast<u16x8*>(aggL + (size_t)node * 128 + c * 8) = lo;
    }
}

// ---------------- MFMA GEMM: C = [agg|h] @ Wt^T + bias, split-bf16 3-term ----------------
// h-half A fragments reconstructed in-register from fp16 h + fp16 residual (err 2^-24).
// Non-LAST epilogue writes h16+r16 (4 B/elem). LAST writes fp32 to d_out only.
template <int RELU, int LAST>
__global__ __launch_bounds__(256) void mfma_gemm_kernel(
    const unsigned short* __restrict__ aggH, const unsigned short* __restrict__ aggL,
    const unsigned short* h16, const unsigned short* r16,
    const unsigned short* __restrict__ WH, const unsigned short* __restrict__ WL,
    const float* __restrict__ bias,
    float* __restrict__ OutF, unsigned short* H16o, unsigned short* R16o)
{
    __shared__ __align__(16) unsigned short Bh[4][128][8];
    __shared__ __align__(16) unsigned short Bl[4][128][8];
    const int tid = threadIdx.x;
    const int lane = tid & 63;
    const int wv = tid >> 6;           // 0..3
    const int m16 = lane & 15;
    const int kg = lane >> 4;          // 0..3
    const int blockRow = blockIdx.x * 64;
    const int rowg = blockRow + wv * 16 + m16;
    const int rowc = min(rowg, N_NODES - 1);

    f32x4 acc[8];
#pragma unroll
    for (int t = 0; t < 8; ++t) acc[t] = (f32x4){0.f, 0.f, 0.f, 0.f};

    for (int ks = 0; ks < 8; ++ks) {
        const int kc = ks * 32;
        const int kcol = kc & 127;
        bfrag a_h, a_l;
        if (kc < 128) {
            a_h = *reinterpret_cast<const bfrag*>(aggH + (size_t)rowc * 128 + kcol + kg * 8);
            a_l = *reinterpret_cast<const bfrag*>(aggL + (size_t)rowc * 128 + kcol + kg * 8);
        } else {
            u16x8 hv = *reinterpret_cast<const u16x8*>(h16 + (size_t)rowc * 128 + kcol + kg * 8);
            u16x8 rv = *reinterpret_cast<const u16x8*>(r16 + (size_t)rowc * 128 + kcol + kg * 8);
#pragma unroll
            for (int j = 0; j < 8; ++j) {
                float v = h2f(hv[j]) + h2f(rv[j]);
                union { float f; unsigned u; } a; a.f = v;
                unsigned hu = a.u & 0xFFFF0000u;   // truncate-split: hi
                a_h[j] = (short)(hu >> 16);
                union { unsigned u; float f; } b; b.u = hu;
                a_l[j] = (short)f2bf_rn(v - b.f);
            }
        }
        {
            const unsigned short* g0 = WH + (size_t)lane * 256 + kc + wv * 8;
            const unsigned short* g1 = WH + (size_t)(64 + lane) * 256 + kc + wv * 8;
            GLOAD16(g0, (char*)&Bh[0][0][0] + wv * 2048);
            GLOAD16(g1, (char*)&Bh[0][0][0] + wv * 2048 + 1024);
            const unsigned short* g2 = WL + (size_t)lane * 256 + kc + wv * 8;
            const unsigned short* g3 = WL + (size_t)(64 + lane) * 256 + kc + wv * 8;
            GLOAD16(g2, (char*)&Bl[0][0][0] + wv * 2048);
            GLOAD16(g3, (char*)&Bl[0][0][0] + wv * 2048 + 1024);
        }
        __syncthreads();
#pragma unroll
        for (int t = 0; t < 8; ++t) {
            bfrag bh = *reinterpret_cast<const bfrag*>(&Bh[kg][t * 16 + m16][0]);
            bfrag bl = *reinterpret_cast<const bfrag*>(&Bl[kg][t * 16 + m16][0]);
            acc[t] = __builtin_amdgcn_mfma_f32_16x16x32_bf16(a_h, bh, acc[t], 0, 0, 0);
            acc[t] = __builtin_amdgcn_mfma_f32_16x16x32_bf16(a_l, bh, acc[t], 0, 0, 0);
            acc[t] = __builtin_amdgcn_mfma_f32_16x16x32_bf16(a_h, bl, acc[t], 0, 0, 0);
        }
        __syncthreads();
    }

#pragma unroll
    for (int t = 0; t < 8; ++t) {
        int col = t * 16 + m16;
        float bv = bias[col];
#pragma unroll
        for (int r = 0; r < 4; ++r) {
            int row = blockRow + wv * 16 + kg * 4 + r;
            if (row >= N_NODES) continue;
            float v = acc[t][r] + bv;
            if (RELU) v = fmaxf(v, 0.f);
            if (LAST) {
                OutF[(size_t)row * 128 + col] = v;
            } else {
                unsigned short h = f2h(v);
                H16o[(size_t)row * 128 + col] = h;
                R16o[(size_t)row * 128 + col] = f2h(v - h2f(h));
            }
        }
    }
}

extern "C" void kernel_launch(void* const* d_in, const int* in_sizes, int n_in,
                              void* d_out, int out_size, void* d_ws, size_t ws_size,
                              hipStream_t stream) {
    const float* x  = (const float*)d_in[0];
    const int*   ei = (const int*)d_in[1];
    const float* Wl = (const float*)d_in[2];
    const float* bl = (const float*)d_in[3];
    const float* Wr = (const float*)d_in[4];
    float* out = (float*)d_out;
    char* ws = (char*)d_ws;

    int*            flag     = (int*)(ws + 0);
    int*            partials = (int*)(ws + 1024);
    int*            deg      = (int*)(ws + 4096);
    int*            offs     = (int*)(ws + 204800);
    int*            cursor1  = (int*)(ws + 405504);
    float*          invd     = (float*)(ws + 606208);
    int*            src      = (int*)(ws + 806912);
    int*            dst      = (int*)(ws + 4007936);
    int*            csr      = (int*)(ws + 7208960);
    unsigned short* WH       = (unsigned short*)(ws + 10409984);
    unsigned short* WL       = (unsigned short*)(ws + 10606592);
    unsigned short* aggH     = (unsigned short*)(ws + 10804224);
    unsigned short* aggL     = (unsigned short*)(ws + 23604224);
    unsigned short* r16      = (unsigned short*)(ws + 36405248);
    unsigned short* h16      = (unsigned short*)(ws + 49205248);
    int*            packed   = (int*)aggH;          // 3.2 MB, dead before first aggregate write

    zero_deg_kernel<<<SCAN_NBLK, 256, 0, stream>>>(deg);
    detect_dtype_kernel<<<1, 256, 0, stream>>>((const unsigned int*)ei, flag);
    convert_hist_kernel<<<(N_EDGES + 255) / 256, 256, 0, stream>>>(ei, flag, src, dst, deg);
    partial_sum_kernel<<<SCAN_NBLK, 256, 0, stream>>>(deg, partials);
    scan_partials_kernel<<<1, 256, 0, stream>>>(partials, offs);
    scan_final_kernel<<<SCAN_NBLK, 256, 0, stream>>>(deg, partials, offs, cursor1, invd);
    pass1_kernel<<<(N_EDGES + 4095) / 4096, 256, 0, stream>>>(src, dst, cursor1, packed);
    pass2_kernel<<<NBUCK, 256, 0, stream>>>(offs, packed, csr);
    prep_w_kernel<<<(N_LAYERS * 128 * 256 + 255) / 256, 256, 0, stream>>>(Wl, Wr, WH, WL);
    split_x_kernel<<<(N_NODES * 32 + 255) / 256, 256, 0, stream>>>(x, h16, r16);

    const int aggGrid = N_NODES / 4;            // 12500
    const int gemmGrid = (N_NODES + 63) / 64;   // 782

    // layer 0
    aggregate_kernel<<<aggGrid, 256, 0, stream>>>(h16, offs, csr, invd, aggH, aggL);
    mfma_gemm_kernel<1, 0><<<gemmGrid, 256, 0, stream>>>(aggH, aggL, h16, r16,
        WH + 0 * 32768, WL + 0 * 32768, bl + 0, nullptr, h16, r16);
    // layer 1
    aggregate_kernel<<<aggGrid, 256, 0, stream>>>(h16, offs, csr, invd, aggH, aggL);
    mfma_gemm_kernel<1, 0><<<gemmGrid, 256, 0, stream>>>(aggH, aggL, h16, r16,
        WH + 1 * 32768, WL + 1 * 32768, bl + 128, nullptr, h16, r16);
    // layer 2: final fp32 into d_out (d_out no longer aliased by h16)
    aggregate_kernel<<<aggGrid, 256, 0, stream>>>(h16, offs, csr, invd, aggH, aggL);
    mfma_gemm_kernel<0, 1><<<gemmGrid, 256, 0, stream>>>(aggH, aggL, h16, r16,
        WH + 2 * 32768, WL + 2 * 32768, bl + 256, out, nullptr, nullptr);
}